// Round 17
// baseline (249.537 us; speedup 1.0000x reference)
//
#include <hip/hip_runtime.h>

#define H 128
#define IN_DIM 256
#define OUT_DIM 40
#define EPS 1e-5f

typedef unsigned short ushortT;
typedef __attribute__((ext_vector_type(8))) short bf16x8;
typedef __attribute__((ext_vector_type(4))) float f32x4;

static __device__ __forceinline__ ushortT f2bf(float f) {
    union { float f; unsigned u; } v; v.f = f;
    unsigned r = v.u + 0x7FFF + ((v.u >> 16) & 1);   // RNE
    return (ushortT)(r >> 16);
}
static __device__ __forceinline__ unsigned pk2(float a, float b) {
    return (unsigned)f2bf(a) | ((unsigned)f2bf(b) << 16);
}
static __device__ __forceinline__ float bflo(unsigned v) {
    union { unsigned u; float f; } t; t.u = v << 16; return t.f;
}
static __device__ __forceinline__ float bfhi(unsigned v) {
    union { unsigned u; float f; } t; t.u = v & 0xFFFF0000u; return t.f;
}
static __device__ __forceinline__ float i2f(int v) {
    union { int i; float f; } t; t.i = v; return t.f;
}
static __device__ __forceinline__ int f2i(float v) {
    union { float f; int i; } t; t.f = v; return t.i;
}

// ---------------- weight prep: transpose + bf16 (also zeroes cnt + stats) ----------------

__global__ __launch_bounds__(256) void prep_weights(const float* __restrict__ W0, const float* __restrict__ pW,
                                                    const float* __restrict__ W1, const float* __restrict__ hW,
                                                    ushortT* __restrict__ Wt0, ushortT* __restrict__ WtP,
                                                    ushortT* __restrict__ Wt1, ushortT* __restrict__ WtH,
                                                    int* __restrict__ cnt, float* __restrict__ stats, int N) {
    int i = blockIdx.x * 256 + threadIdx.x;
    if (i < 32768) { int n = i >> 8, k = i & 255; Wt0[i] = f2bf(W0[k * 128 + n]); WtP[i] = f2bf(pW[k * 128 + n]); }
    if (i < 16384) { int n = i >> 7, k = i & 127; Wt1[i] = f2bf(W1[k * 128 + n]); }
    if (i < 6144)  { int n = i >> 7, k = i & 127; WtH[i] = (n < OUT_DIM) ? f2bf(hW[k * OUT_DIM + n]) : (ushortT)0; }
    if (i < N) cnt[i] = 0;
    if (i < 512) stats[i] = 0.f;
}

// ---------------- degree count: XCD-partitioned (separate dispatch, R8 shape) ----------------

__global__ __launch_bounds__(256) void count_xcd(const int* __restrict__ ei, int E, int nper,
                                                 int* __restrict__ cnt) {
    int xcd = blockIdx.x & 7;
    int nchunk = gridDim.x >> 3;
    int chunk = blockIdx.x >> 3;
    int csz = (E + nchunk - 1) / nchunk;
    int beg = chunk * csz;
    int end = min(E, beg + csz);
    for (int e = beg + (int)threadIdx.x; e < end; e += 256) {
        int c = ei[E + e];
        if (c / nper == xcd) atomicAdd(&cnt[c], 1);
    }
}

// ---------------- GEMM0: dual (h = x@W0, proj = x@pW + pb), K=256 in 2 dbuf chunks, LDS epilogue ----------------
// 512 threads (8 waves), BM=64. waves 0-3: W0 -> Oh; waves 4-7: pW -> Op. wave cols = (w&3)*32 + [0,32).

static __device__ __forceinline__ void g0_loads(const float* __restrict__ X, int brow, int kc,
                                                int tid, int N, float4 pf[4]) {
#pragma unroll
    for (int i = 0; i < 4; ++i) {
        int idx = i * 512 + tid;
        int row = idx >> 5, c4 = idx & 31;
        int gr = brow + row;
        pf[i] = make_float4(0.f, 0.f, 0.f, 0.f);
        if (gr < N) pf[i] = *(const float4*)&X[(size_t)gr * IN_DIM + kc * 128 + c4 * 4];
    }
}
static __device__ __forceinline__ void g0_write(ushortT* __restrict__ Sbuf, int tid, const float4 pf[4]) {
#pragma unroll
    for (int i = 0; i < 4; ++i) {
        int idx = i * 512 + tid;
        int row = idx >> 5, c4 = idx & 31;
        uint2 p;
        p.x = pk2(pf[i].x, pf[i].y);
        p.y = pk2(pf[i].z, pf[i].w);
        *(uint2*)&Sbuf[row * 136 + c4 * 4] = p;
    }
}

__global__ __launch_bounds__(512) void mgemm0d(const float* __restrict__ X,
                                               const ushortT* __restrict__ Wt0,
                                               const ushortT* __restrict__ WtP,
                                               const float* __restrict__ pb,
                                               ushortT* __restrict__ Oh,
                                               ushortT* __restrict__ Op,
                                               int N) {
    __shared__ __align__(16) ushortT S2[2][64 * 136];
    int tid = threadIdx.x;
    int brow = blockIdx.x * 64;
    int w = tid >> 6, lane = tid & 63;
    int lm = lane & 15, lk = lane >> 4;
    int mat = w >> 2;
    int colbase = (w & 3) * 32;
    const ushortT* Wt = mat ? WtP : Wt0;

    bf16x8 breg[2][8];
#pragma unroll
    for (int nt = 0; nt < 2; ++nt)
#pragma unroll
        for (int kk = 0; kk < 8; ++kk)
            breg[nt][kk] = *(const bf16x8*)&Wt[(size_t)(colbase + nt * 16 + lm) * IN_DIM + kk * 32 + lk * 8];
    float bb[2];
    bb[0] = mat ? pb[colbase + lm] : 0.f;
    bb[1] = mat ? pb[colbase + 16 + lm] : 0.f;

    float4 pf[4];
    g0_loads(X, brow, 0, tid, N, pf);
    g0_write(S2[0], tid, pf);
    __syncthreads();                                   // buf0 staged
    g0_loads(X, brow, 1, tid, N, pf);                  // issue chunk1 early

    f32x4 acc[4][2];
#pragma unroll
    for (int mt = 0; mt < 4; ++mt)
#pragma unroll
        for (int nt = 0; nt < 2; ++nt) acc[mt][nt] = (f32x4)0.f;

#pragma unroll
    for (int kk = 0; kk < 4; ++kk) {
        bf16x8 af[4];
#pragma unroll
        for (int mt = 0; mt < 4; ++mt)
            af[mt] = *(const bf16x8*)&S2[0][(mt * 16 + lm) * 136 + kk * 32 + lk * 8];
#pragma unroll
        for (int nt = 0; nt < 2; ++nt)
#pragma unroll
            for (int mt = 0; mt < 4; ++mt)
                acc[mt][nt] = __builtin_amdgcn_mfma_f32_16x16x32_bf16(af[mt], breg[nt][kk], acc[mt][nt], 0, 0, 0);
    }
    g0_write(S2[1], tid, pf);
    __syncthreads();                                   // buf1 staged
#pragma unroll
    for (int kk = 0; kk < 4; ++kk) {
        bf16x8 af[4];
#pragma unroll
        for (int mt = 0; mt < 4; ++mt)
            af[mt] = *(const bf16x8*)&S2[1][(mt * 16 + lm) * 136 + kk * 32 + lk * 8];
#pragma unroll
        for (int nt = 0; nt < 2; ++nt)
#pragma unroll
            for (int mt = 0; mt < 4; ++mt)
                acc[mt][nt] = __builtin_amdgcn_mfma_f32_16x16x32_bf16(af[mt], breg[nt][4 + kk], acc[mt][nt], 0, 0, 0);
    }
    __syncthreads();                                   // all LDS reads done; reuse as C
#pragma unroll
    for (int mt = 0; mt < 4; ++mt)
#pragma unroll
        for (int nt = 0; nt < 2; ++nt) {
            int col = colbase + nt * 16 + lm;
#pragma unroll
            for (int j = 0; j < 4; ++j) {
                int row = mt * 16 + lk * 4 + j;
                S2[mat][row * 136 + col] = f2bf(acc[mt][nt][j] + bb[nt]);
            }
        }
    __syncthreads();
#pragma unroll
    for (int i = 0; i < 4; ++i) {
        int idx = i * 512 + tid;
        int m2 = idx >> 10;
        int rem = idx & 1023;
        int row = rem >> 4, colq = rem & 15;
        int gr = brow + row;
        if (gr < N) {
            uint4 v = *(const uint4*)&S2[m2][row * 136 + colq * 8];
            ushortT* O = m2 ? Op : Oh;
            *(uint4*)&O[(size_t)gr * 128 + colq * 8] = v;
        }
    }
}

// ---------------- scan hierarchy ----------------

__global__ __launch_bounds__(256) void scan_block_sum(const int* __restrict__ cnt, int* __restrict__ bsum,
                                                      float* __restrict__ dis, int N) {
    __shared__ int s[256];
    int i = blockIdx.x * 256 + threadIdx.x;
    int c = (i < N) ? cnt[i] : -1;
    int v = (i < N) ? c + 1 : 0;
    if (i < N) dis[i] = rsqrtf((float)c + 2.0f);
    s[threadIdx.x] = v;
    __syncthreads();
    for (int o = 128; o > 0; o >>= 1) {
        if (threadIdx.x < o) s[threadIdx.x] += s[threadIdx.x + o];
        __syncthreads();
    }
    if (threadIdx.x == 0) bsum[blockIdx.x] = s[0];
}

__global__ void scan_tops(const int* __restrict__ bsum, int* __restrict__ boff, int* __restrict__ rowptrN, int nb) {
    __shared__ int s[256];
    int t = threadIdx.x;
    int v = (t < nb) ? bsum[t] : 0;
    s[t] = v;
    __syncthreads();
    for (int o = 1; o < 256; o <<= 1) {
        int u = (t >= o) ? s[t - o] : 0;
        __syncthreads();
        s[t] += u;
        __syncthreads();
    }
    if (t < nb) boff[t] = s[t] - v;
    if (t == 255) *rowptrN = s[255];
}

__global__ __launch_bounds__(256) void scan_final(const int* __restrict__ cnt, const int* __restrict__ boff,
                                                  const float* __restrict__ dis,
                                                  int* __restrict__ rowptr, int* __restrict__ cursor,
                                                  int2* __restrict__ recs, int N) {
    __shared__ int s[256];
    int t = threadIdx.x;
    int i = blockIdx.x * 256 + t;
    int v = (i < N) ? cnt[i] + 1 : 0;
    s[t] = v;
    __syncthreads();
    for (int o = 1; o < 256; o <<= 1) {
        int u = (t >= o) ? s[t - o] : 0;
        __syncthreads();
        s[t] += u;
        __syncthreads();
    }
    if (i < N) {
        int e = boff[blockIdx.x] + s[t] - v;
        rowptr[i] = e;
        cursor[i] = e + 1;                    // slot e holds the self record
        float d = dis[i];
        int2 r; r.x = i; r.y = f2i(2.0f * d * d);
        recs[e] = r;
    }
}

// XCD-partitioned fill; writes (src, dis[src]*dis[dst]) records
__global__ __launch_bounds__(256) void fill_xcd(const int* __restrict__ ei, int E, int nper,
                                                const float* __restrict__ dis,
                                                int* __restrict__ cursor, int2* __restrict__ recs) {
    int xcd = blockIdx.x & 7;
    int nchunk = gridDim.x >> 3;
    int chunk = blockIdx.x >> 3;
    int csz = (E + nchunk - 1) / nchunk;
    int beg = chunk * csz;
    int end = min(E, beg + csz);
    for (int e = beg + (int)threadIdx.x; e < end; e += 256) {
        int c = ei[E + e];
        if (c / nper == xcd) {
            int r = ei[e];
            int slot = atomicAdd(&cursor[c], 1);
            int2 rec; rec.x = r; rec.y = f2i(dis[r] * dis[c]);
            recs[slot] = rec;
        }
    }
}

// ---------------- aggregation: wave per node, half-wave split, 4 records in flight per half ----------------

__global__ __launch_bounds__(256) void aggregate_rec(const ushortT* __restrict__ h,
                                                     const int* __restrict__ rowptr,
                                                     const int2* __restrict__ recs,
                                                     ushortT* __restrict__ aggb, int N) {
    int n = blockIdx.x * 4 + (threadIdx.x >> 6);
    if (n >= N) return;
    int lane = threadIdx.x & 63;
    int half = lane >> 5, cl = lane & 31;
    int beg = rowptr[n], end = rowptr[n + 1];
    const uint2* h2 = (const uint2*)h;           // 8B units; row stride 32
    float a0 = 0.f, a1 = 0.f, a2 = 0.f, a3 = 0.f;
    float b0 = 0.f, b1 = 0.f, b2 = 0.f, b3 = 0.f;
    float c0 = 0.f, c1 = 0.f, c2 = 0.f, c3 = 0.f;
    float d0 = 0.f, d1 = 0.f, d2 = 0.f, d3 = 0.f;
    int idx = beg + half;
    // main: 4 records per half per iteration (8 rows in flight per wave)
    for (; idx + 6 < end; idx += 8) {
        int2 r0 = recs[idx];
        int2 r1 = recs[idx + 2];
        int2 r2 = recs[idx + 4];
        int2 r3 = recs[idx + 6];
        uint2 v0 = h2[(size_t)r0.x * 32 + cl];
        uint2 v1 = h2[(size_t)r1.x * 32 + cl];
        uint2 v2 = h2[(size_t)r2.x * 32 + cl];
        uint2 v3 = h2[(size_t)r3.x * 32 + cl];
        float n0 = i2f(r0.y), n1 = i2f(r1.y), n2 = i2f(r2.y), n3 = i2f(r3.y);
        a0 = fmaf(n0, bflo(v0.x), a0); a1 = fmaf(n0, bfhi(v0.x), a1);
        a2 = fmaf(n0, bflo(v0.y), a2); a3 = fmaf(n0, bfhi(v0.y), a3);
        b0 = fmaf(n1, bflo(v1.x), b0); b1 = fmaf(n1, bfhi(v1.x), b1);
        b2 = fmaf(n1, bflo(v1.y), b2); b3 = fmaf(n1, bfhi(v1.y), b3);
        c0 = fmaf(n2, bflo(v2.x), c0); c1 = fmaf(n2, bfhi(v2.x), c1);
        c2 = fmaf(n2, bflo(v2.y), c2); c3 = fmaf(n2, bfhi(v2.y), c3);
        d0 = fmaf(n3, bflo(v3.x), d0); d1 = fmaf(n3, bfhi(v3.x), d1);
        d2 = fmaf(n3, bflo(v3.y), d2); d3 = fmaf(n3, bfhi(v3.y), d3);
    }
    // tail: up to 3 leftover records per half
    for (; idx < end; idx += 2) {
        int2 r0 = recs[idx];
        uint2 v0 = h2[(size_t)r0.x * 32 + cl];
        float n0 = i2f(r0.y);
        a0 = fmaf(n0, bflo(v0.x), a0); a1 = fmaf(n0, bfhi(v0.x), a1);
        a2 = fmaf(n0, bflo(v0.y), a2); a3 = fmaf(n0, bfhi(v0.y), a3);
    }
    a0 = (a0 + b0) + (c0 + d0);
    a1 = (a1 + b1) + (c1 + d1);
    a2 = (a2 + b2) + (c2 + d2);
    a3 = (a3 + b3) + (c3 + d3);
    a0 += __shfl_xor(a0, 32);
    a1 += __shfl_xor(a1, 32);
    a2 += __shfl_xor(a2, 32);
    a3 += __shfl_xor(a3, 32);
    if (half == 0) {
        uint2 o;
        o.x = pk2(a0, a1);
        o.y = pk2(a2, a3);
        ((uint2*)aggb)[(size_t)n * 32 + cl] = o;
    }
}

// ---------------- BN stats from bf16 (raw sums) ----------------

__global__ __launch_bounds__(256) void stats_bf(const unsigned* __restrict__ v, int totalU,
                                                float* __restrict__ sums) {
    int tid = blockIdx.x * 256 + threadIdx.x;
    int stride = gridDim.x * 256;
    float sx = 0.f, sy = 0.f, qx = 0.f, qy = 0.f;
    for (int i = tid; i < totalU; i += stride) {
        unsigned u = v[i];
        float a = bflo(u), b = bfhi(u);
        sx += a; sy += b;
        qx = fmaf(a, a, qx); qy = fmaf(b, b, qy);
    }
    __shared__ float l0[256], l1[256], l2[256], l3[256];
    int t = threadIdx.x;
    l0[t] = sx; l1[t] = sy; l2[t] = qx; l3[t] = qy;
    __syncthreads();
    if (t < 64) {
        sx = (l0[t] + l0[t + 64]) + (l0[t + 128] + l0[t + 192]);
        sy = (l1[t] + l1[t + 64]) + (l1[t + 128] + l1[t + 192]);
        qx = (l2[t] + l2[t + 64]) + (l2[t + 128] + l2[t + 192]);
        qy = (l3[t] + l3[t + 64]) + (l3[t + 128] + l3[t + 192]);
        atomicAdd(&sums[2 * t], sx);
        atomicAdd(&sums[2 * t + 1], sy);
        atomicAdd(&sums[128 + 2 * t], qx);
        atomicAdd(&sums[128 + 2 * t + 1], qy);
    }
}

// ---------------- GEMM1 fused: x1 = relu(bn0(agg)) + proj (written out), h = x1 @ W1, LDS epilogue ----------------

__global__ __launch_bounds__(512) void mgemm1_fused(const uint4* __restrict__ aggb,
                                                    const uint4* __restrict__ projb,
                                                    const float* __restrict__ stats,
                                                    const float* __restrict__ g,
                                                    const float* __restrict__ be,
                                                    const ushortT* __restrict__ Wt1,
                                                    ushortT* __restrict__ O,
                                                    uint4* __restrict__ x1b,
                                                    int N) {
    __shared__ __align__(16) ushortT S[17408];
    __shared__ float sc[128], sh[128];
    int tid = threadIdx.x;
    int brow = blockIdx.x * 128;

    if (tid < 128) {
        float mean = stats[tid] / (float)N;
        float var = stats[128 + tid] / (float)N - mean * mean;
        float inv = rsqrtf(var + EPS);
        float s = g[tid] * inv;
        sc[tid] = s;
        sh[tid] = be[tid] - mean * s;
    }
    __syncthreads();

#pragma unroll
    for (int i = 0; i < 4; ++i) {
        int idx = i * 512 + tid;
        int row = idx >> 4, q = idx & 15;
        int gr = brow + row;
        uint4 a = make_uint4(0u, 0u, 0u, 0u), p = a;
        if (gr < N) {
            size_t gidx = (size_t)gr * 16 + q;
            a = aggb[gidx];
            p = projb[gidx];
        }
        int ch = q * 8;
        float v0 = fmaxf(fmaf(bflo(a.x), sc[ch + 0], sh[ch + 0]), 0.f) + bflo(p.x);
        float v1 = fmaxf(fmaf(bfhi(a.x), sc[ch + 1], sh[ch + 1]), 0.f) + bfhi(p.x);
        float v2 = fmaxf(fmaf(bflo(a.y), sc[ch + 2], sh[ch + 2]), 0.f) + bflo(p.y);
        float v3 = fmaxf(fmaf(bfhi(a.y), sc[ch + 3], sh[ch + 3]), 0.f) + bfhi(p.y);
        float v4 = fmaxf(fmaf(bflo(a.z), sc[ch + 4], sh[ch + 4]), 0.f) + bflo(p.z);
        float v5 = fmaxf(fmaf(bfhi(a.z), sc[ch + 5], sh[ch + 5]), 0.f) + bfhi(p.z);
        float v6 = fmaxf(fmaf(bflo(a.w), sc[ch + 6], sh[ch + 6]), 0.f) + bflo(p.w);
        float v7 = fmaxf(fmaf(bfhi(a.w), sc[ch + 7], sh[ch + 7]), 0.f) + bfhi(p.w);
        uint4 pv;
        pv.x = pk2(v0, v1);
        pv.y = pk2(v2, v3);
        pv.z = pk2(v4, v5);
        pv.w = pk2(v6, v7);
        *(uint4*)&S[row * 136 + q * 8] = pv;
        if (gr < N) x1b[(size_t)gr * 16 + q] = pv;
    }
    __syncthreads();

    int w = tid >> 6, lane = tid & 63;
    int lm = lane & 15, lk = lane >> 4;
    int rh = (w >> 2) * 64;
    int colbase = (w & 3) * 32;

    bf16x8 breg[2][4];
#pragma unroll
    for (int nt = 0; nt < 2; ++nt)
#pragma unroll
        for (int ks = 0; ks < 4; ++ks)
            breg[nt][ks] = *(const bf16x8*)&Wt1[(size_t)(colbase + nt * 16 + lm) * H + ks * 32 + lk * 8];

    f32x4 acc[4][2];
#pragma unroll
    for (int mt = 0; mt < 4; ++mt)
#pragma unroll
        for (int nt = 0; nt < 2; ++nt) acc[mt][nt] = (f32x4)0.f;

#pragma unroll
    for (int ks = 0; ks < 4; ++ks) {
        bf16x8 af[4];
#pragma unroll
        for (int mt = 0; mt < 4; ++mt)
            af[mt] = *(const bf16x8*)&S[(rh + mt * 16 + lm) * 136 + ks * 32 + lk * 8];
#pragma unroll
        for (int nt = 0; nt < 2; ++nt)
#pragma unroll
            for (int mt = 0; mt < 4; ++mt)
                acc[mt][nt] = __builtin_amdgcn_mfma_f32_16x16x32_bf16(af[mt], breg[nt][ks], acc[mt][nt], 0, 0, 0);
    }

    __syncthreads();
#pragma unroll
    for (int mt = 0; mt < 4; ++mt)
#pragma unroll
        for (int nt = 0; nt < 2; ++nt) {
            int col = colbase + nt * 16 + lm;
#pragma unroll
            for (int j = 0; j < 4; ++j) {
                int row = rh + mt * 16 + lk * 4 + j;
                S[row * 136 + col] = f2bf(acc[mt][nt][j]);
            }
        }
    __syncthreads();
#pragma unroll
    for (int i = 0; i < 4; ++i) {
        int idx = i * 512 + tid;
        int row = idx >> 4, colq = idx & 15;
        int gr = brow + row;
        if (gr < N) {
            uint4 v = *(const uint4*)&S[row * 136 + colq * 8];
            *(uint4*)&O[(size_t)gr * 128 + colq * 8] = v;
        }
    }
}

// ---------------- head: out = (relu(bn1(agg)) + x1) @ hW + hb, x2 inline ----------------

__global__ __launch_bounds__(256) void head_fused(const uint4* __restrict__ aggb,
                                                  const uint4* __restrict__ x1b,
                                                  const float* __restrict__ stats,
                                                  const float* __restrict__ g,
                                                  const float* __restrict__ be,
                                                  const ushortT* __restrict__ WtH,
                                                  const float* __restrict__ hb,
                                                  float* __restrict__ out, int N) {
    __shared__ __align__(16) ushortT As[64][136];
    __shared__ __align__(16) ushortT Bs[48][136];
    __shared__ float sc[128], sh[128];

    int tid = threadIdx.x;
    int brow = blockIdx.x * 64;
    int w = tid >> 6, lane = tid & 63;
    int lm = lane & 15, lk = lane >> 4;

    if (tid < 128) {
        float mean = stats[tid] / (float)N;
        float var = stats[128 + tid] / (float)N - mean * mean;
        float inv = rsqrtf(var + EPS);
        float s = g[tid] * inv;
        sc[tid] = s;
        sh[tid] = be[tid] - mean * s;
    }
    if (tid < 192) {
        int row = tid >> 2, q = tid & 3;
        const uint4* src = (const uint4*)&WtH[(size_t)row * H + q * 32];
        uint4 a = src[0], b = src[1], c = src[2], d = src[3];
        uint4* dst = (uint4*)&Bs[row][q * 32];
        dst[0] = a; dst[1] = b; dst[2] = c; dst[3] = d;
    }
    __syncthreads();
#pragma unroll
    for (int k = 0; k < 4; ++k) {
        int idx = k * 256 + tid;
        int row = idx >> 4, colq = idx & 15;
        int gr = brow + row;
        uint4 a = make_uint4(0u, 0u, 0u, 0u), x = a;
        if (gr < N) {
            size_t gidx = (size_t)brow * 16 + idx;
            a = aggb[gidx];
            x = x1b[gidx];
        }
        int ch = colq * 8;
        float v0 = fmaxf(fmaf(bflo(a.x), sc[ch + 0], sh[ch + 0]), 0.f) + bflo(x.x);
        float v1 = fmaxf(fmaf(bfhi(a.x), sc[ch + 1], sh[ch + 1]), 0.f) + bfhi(x.x);
        float v2 = fmaxf(fmaf(bflo(a.y), sc[ch + 2], sh[ch + 2]), 0.f) + bflo(x.y);
        float v3 = fmaxf(fmaf(bfhi(a.y), sc[ch + 3], sh[ch + 3]), 0.f) + bfhi(x.y);
        float v4 = fmaxf(fmaf(bflo(a.z), sc[ch + 4], sh[ch + 4]), 0.f) + bflo(x.z);
        float v5 = fmaxf(fmaf(bfhi(a.z), sc[ch + 5], sh[ch + 5]), 0.f) + bfhi(x.z);
        float v6 = fmaxf(fmaf(bflo(a.w), sc[ch + 6], sh[ch + 6]), 0.f) + bflo(x.w);
        float v7 = fmaxf(fmaf(bfhi(a.w), sc[ch + 7], sh[ch + 7]), 0.f) + bfhi(x.w);
        uint4 pv;
        pv.x = pk2(v0, v1);
        pv.y = pk2(v2, v3);
        pv.z = pk2(v4, v5);
        pv.w = pk2(v6, v7);
        *(uint4*)&As[row][colq * 8] = pv;
    }
    __syncthreads();

    f32x4 acc[3];
#pragma unroll
    for (int nt = 0; nt < 3; ++nt) acc[nt] = (f32x4)0.f;
#pragma unroll
    for (int ks = 0; ks < 4; ++ks) {
        bf16x8 a = *(const bf16x8*)&As[w * 16 + lm][ks * 32 + lk * 8];
#pragma unroll
        for (int nt = 0; nt < 3; ++nt) {
            bf16x8 b = *(const bf16x8*)&Bs[nt * 16 + lm][ks * 32 + lk * 8];
            acc[nt] = __builtin_amdgcn_mfma_f32_16x16x32_bf16(a, b, acc[nt], 0, 0, 0);
        }
    }
#pragma unroll
    for (int nt = 0; nt < 3; ++nt) {
        int col = nt * 16 + lm;
        if (col < OUT_DIM) {
            float bbv = hb[col];
#pragma unroll
            for (int j = 0; j < 4; ++j) {
                int r = brow + w * 16 + lk * 4 + j;
                if (r < N) out[(size_t)r * OUT_DIM + col] = acc[nt][j] + bbv;
            }
        }
    }
}

// ---------------- launch ----------------

extern "C" void kernel_launch(void* const* d_in, const int* in_sizes, int n_in,
                              void* d_out, int out_size, void* d_ws, size_t ws_size,
                              hipStream_t stream) {
    const float* x   = (const float*)d_in[0];
    const int*   ei  = (const int*)d_in[1];
    const float* W0  = (const float*)d_in[2];
    // d_in[3] = b0: cancels in BatchNorm
    const float* g0  = (const float*)d_in[4];
    const float* be0 = (const float*)d_in[5];
    const float* pW  = (const float*)d_in[6];
    const float* pb  = (const float*)d_in[7];
    const float* W1  = (const float*)d_in[8];
    // d_in[9] = b1: cancels in BatchNorm
    const float* g1  = (const float*)d_in[10];
    const float* be1 = (const float*)d_in[11];
    const float* hW  = (const float*)d_in[12];
    const float* hb  = (const float*)d_in[13];
    float* out = (float*)d_out;

    int N = in_sizes[0] / IN_DIM;
    int E = in_sizes[1] / 2;
    size_t NH = (size_t)N * H;

    // workspace layout (all bf16 intermediates)
    ushortT* hb16   = (ushortT*)d_ws;            // [N,128] conv input h
    ushortT* aggb   = hb16 + NH;                 // [N,128] aggregated
    ushortT* projb  = aggb + NH;                 // [N,128] proj (block0)
    ushortT* x1b    = projb + NH;                // [N,128] x1
    float*   dis    = (float*)(x1b + NH);        // [N]
    int*     cnt    = (int*)(dis + N);           // [N]
    int*     rowptr = cnt + N;                   // [N+1]
    int*     cursor = rowptr + (N + 1);          // [N]
    int2*    recs   = (int2*)(cursor + N);       // [E+N] (8B-aligned)
    float*   stats  = (float*)(recs + (E + N));  // [512]: conv0 then conv1
    ushortT* Wt0    = (ushortT*)(stats + 512);   // [128*256]
    ushortT* WtP    = Wt0 + 128 * 256;           // [128*256]
    ushortT* Wt1    = WtP + 128 * 256;           // [128*128]
    ushortT* WtH    = Wt1 + 128 * 128;           // [48*128]
    int*     bsum   = (int*)(WtH + 48 * 128);    // [256]
    int*     boff   = bsum + 256;                // [256]
    float*   stats0 = stats;
    float*   stats1 = stats + 256;

    int nb = (N + 255) / 256;
    int g64 = (N + 63) / 64;
    int g128 = (N + 127) / 128;
    int gAgg = (N + 3) / 4;
    int nper = (N + 7) / 8;

    // prep (weights + zero cnt/stats), then count (separate), then GEMM0 (separate)
    prep_weights<<<196, 256, 0, stream>>>(W0, pW, W1, hW, Wt0, WtP, Wt1, WtH, cnt, stats, N);
    count_xcd<<<2048, 256, 0, stream>>>(ei, E, nper, cnt);
    mgemm0d<<<g64, 512, 0, stream>>>(x, Wt0, WtP, pb, hb16, projb, N);

    // CSR offsets + records
    scan_block_sum<<<nb, 256, 0, stream>>>(cnt, bsum, dis, N);
    scan_tops<<<1, 256, 0, stream>>>(bsum, boff, &rowptr[N], nb);
    scan_final<<<nb, 256, 0, stream>>>(cnt, boff, dis, rowptr, cursor, recs, N);
    fill_xcd<<<2048, 256, 0, stream>>>(ei, E, nper, dis, cursor, recs);

    // block 0
    aggregate_rec<<<gAgg, 256, 0, stream>>>(hb16, rowptr, recs, aggb, N);
    stats_bf<<<256, 256, 0, stream>>>((const unsigned*)aggb, (int)(NH / 2), stats0);

    // block 1 (x1 = relu(bn0(agg)) + proj fused into GEMM1's staging; x1 also written for head)
    mgemm1_fused<<<g128, 512, 0, stream>>>((const uint4*)aggb, (const uint4*)projb, stats0, g0, be0,
                                           Wt1, hb16, (uint4*)x1b, N);
    aggregate_rec<<<gAgg, 256, 0, stream>>>(hb16, rowptr, recs, aggb, N);
    stats_bf<<<256, 256, 0, stream>>>((const unsigned*)aggb, (int)(NH / 2), stats1);

    // head (x2 computed inline)
    head_fused<<<g64, 256, 0, stream>>>((const uint4*)aggb, (const uint4*)x1b, stats1, g1, be1,
                                        WtH, hb, out, N);
}

// Round 18
// 235.959 us; speedup vs baseline: 1.0575x; 1.0575x over previous
//
#include <hip/hip_runtime.h>

#define H 128
#define IN_DIM 256
#define OUT_DIM 40
#define EPS 1e-5f

typedef unsigned short ushortT;
typedef __attribute__((ext_vector_type(8))) short bf16x8;
typedef __attribute__((ext_vector_type(4))) float f32x4;

static __device__ __forceinline__ ushortT f2bf(float f) {
    union { float f; unsigned u; } v; v.f = f;
    unsigned r = v.u + 0x7FFF + ((v.u >> 16) & 1);   // RNE
    return (ushortT)(r >> 16);
}
static __device__ __forceinline__ unsigned pk2(float a, float b) {
    return (unsigned)f2bf(a) | ((unsigned)f2bf(b) << 16);
}
static __device__ __forceinline__ float bflo(unsigned v) {
    union { unsigned u; float f; } t; t.u = v << 16; return t.f;
}
static __device__ __forceinline__ float bfhi(unsigned v) {
    union { unsigned u; float f; } t; t.u = v & 0xFFFF0000u; return t.f;
}
static __device__ __forceinline__ float i2f(int v) {
    union { int i; float f; } t; t.i = v; return t.f;
}
static __device__ __forceinline__ int f2i(float v) {
    union { float f; int i; } t; t.f = v; return t.i;
}

// ---------------- weight prep: transpose + bf16 (also zeroes cnt + stats) ----------------

__global__ __launch_bounds__(256) void prep_weights(const float* __restrict__ W0, const float* __restrict__ pW,
                                                    const float* __restrict__ W1, const float* __restrict__ hW,
                                                    ushortT* __restrict__ Wt0, ushortT* __restrict__ WtP,
                                                    ushortT* __restrict__ Wt1, ushortT* __restrict__ WtH,
                                                    int* __restrict__ cnt, float* __restrict__ stats, int N) {
    int i = blockIdx.x * 256 + threadIdx.x;
    if (i < 32768) { int n = i >> 8, k = i & 255; Wt0[i] = f2bf(W0[k * 128 + n]); WtP[i] = f2bf(pW[k * 128 + n]); }
    if (i < 16384) { int n = i >> 7, k = i & 127; Wt1[i] = f2bf(W1[k * 128 + n]); }
    if (i < 6144)  { int n = i >> 7, k = i & 127; WtH[i] = (n < OUT_DIM) ? f2bf(hW[k * OUT_DIM + n]) : (ushortT)0; }
    if (i < N) cnt[i] = 0;
    if (i < 512) stats[i] = 0.f;
}

// ---------------- GEMM0 (BM=128, single-mat per block, XCD-paired tiles) + degree count ----------------
// GEMM role: blocks grouped in 16s; bids [16g,16g+8) = mat0 of tiles 8g..8g+7,
//   bids [16g+8,16g+16) = mat1 of the same tiles -> tile's two blocks share bid%8 (same XCD, L2 reuse of A).
// blocks [gemmBlocks, ...): XCD-partitioned degree count.

__global__ __launch_bounds__(512) void gemm0_count(const float* __restrict__ X,
                                                   const ushortT* __restrict__ Wt0,
                                                   const ushortT* __restrict__ WtP,
                                                   const float* __restrict__ pb,
                                                   ushortT* __restrict__ Oh,
                                                   ushortT* __restrict__ Op,
                                                   const int* __restrict__ ei,
                                                   int* __restrict__ cnt,
                                                   int N, int E, int nper,
                                                   int gemmBlocks, int ntiles) {
    __shared__ __align__(16) ushortT S[128 * 136];   // A chunk staging; reused as C in epilogue
    int tid = threadIdx.x;

    if (blockIdx.x >= gemmBlocks) {
        // ---- count role ----
        int cbid = blockIdx.x - gemmBlocks;
        int xcd = cbid & 7;
        int nchunk = (gridDim.x - gemmBlocks) >> 3;
        int chunk = cbid >> 3;
        int csz = (E + nchunk - 1) / nchunk;
        int beg = chunk * csz;
        int end = min(E, beg + csz);
        for (int e = beg + tid; e < end; e += 512) {
            int c = ei[E + e];
            if (c / nper == xcd) atomicAdd(&cnt[c], 1);
        }
        return;
    }

    // ---- GEMM role (XCD-paired mapping) ----
    int gb = blockIdx.x;
    int mat = (gb >> 3) & 1;
    int tile = ((gb >> 4) << 3) | (gb & 7);
    if (tile >= ntiles) return;
    int brow = tile * 128;
    int w = tid >> 6, lane = tid & 63;
    int lm = lane & 15, lk = lane >> 4;
    int rh = (w >> 2) * 64;
    int colbase = (w & 3) * 32;
    const ushortT* Wt = mat ? WtP : Wt0;
    float bb0 = mat ? pb[colbase + lm] : 0.f;
    float bb1 = mat ? pb[colbase + 16 + lm] : 0.f;
    ushortT* O = mat ? Op : Oh;

    f32x4 acc[4][2];
#pragma unroll
    for (int mt = 0; mt < 4; ++mt)
#pragma unroll
        for (int nt = 0; nt < 2; ++nt) acc[mt][nt] = (f32x4)0.f;

#pragma unroll
    for (int kc = 0; kc < 2; ++kc) {
        if (kc) __syncthreads();                   // chunk0 reads done before overwrite
        // stage A chunk: 128 rows x 128 k, fp32 -> bf16 (4096 float4, 8/thread, coalesced)
#pragma unroll
        for (int i = 0; i < 8; ++i) {
            int idx = i * 512 + tid;
            int row = idx >> 5, c4 = idx & 31;
            int gr = brow + row;
            float4 v = make_float4(0.f, 0.f, 0.f, 0.f);
            if (gr < N) v = *(const float4*)&X[(size_t)gr * IN_DIM + kc * 128 + c4 * 4];
            uint2 p;
            p.x = pk2(v.x, v.y);
            p.y = pk2(v.z, v.w);
            *(uint2*)&S[row * 136 + c4 * 4] = p;
        }
        __syncthreads();
        // B for this chunk (32 VGPRs)
        bf16x8 breg[2][4];
#pragma unroll
        for (int nt = 0; nt < 2; ++nt)
#pragma unroll
            for (int ks = 0; ks < 4; ++ks)
                breg[nt][ks] = *(const bf16x8*)&Wt[(size_t)(colbase + nt * 16 + lm) * IN_DIM + kc * 128 + ks * 32 + lk * 8];
#pragma unroll
        for (int ks = 0; ks < 4; ++ks) {
            bf16x8 af[4];
#pragma unroll
            for (int mt = 0; mt < 4; ++mt)
                af[mt] = *(const bf16x8*)&S[(rh + mt * 16 + lm) * 136 + ks * 32 + lk * 8];
#pragma unroll
            for (int nt = 0; nt < 2; ++nt)
#pragma unroll
                for (int mt = 0; mt < 4; ++mt)
                    acc[mt][nt] = __builtin_amdgcn_mfma_f32_16x16x32_bf16(af[mt], breg[nt][ks], acc[mt][nt], 0, 0, 0);
        }
    }

    __syncthreads();                               // all A reads done; reuse S as C [128][136]
#pragma unroll
    for (int mt = 0; mt < 4; ++mt)
#pragma unroll
        for (int nt = 0; nt < 2; ++nt) {
            int col = colbase + nt * 16 + lm;
            float bb = nt ? bb1 : bb0;
#pragma unroll
            for (int j = 0; j < 4; ++j) {
                int row = rh + mt * 16 + lk * 4 + j;
                S[row * 136 + col] = f2bf(acc[mt][nt][j] + bb);
            }
        }
    __syncthreads();
    // coalesced stores: 2048 uint4 (128 rows x 16 uint4), 4/thread
#pragma unroll
    for (int i = 0; i < 4; ++i) {
        int idx = i * 512 + tid;
        int row = idx >> 4, colq = idx & 15;
        int gr = brow + row;
        if (gr < N) {
            uint4 v = *(const uint4*)&S[row * 136 + colq * 8];
            *(uint4*)&O[(size_t)gr * 128 + colq * 8] = v;
        }
    }
}

// ---------------- scan hierarchy ----------------

__global__ __launch_bounds__(256) void scan_block_sum(const int* __restrict__ cnt, int* __restrict__ bsum,
                                                      float* __restrict__ dis, int N) {
    __shared__ int s[256];
    int i = blockIdx.x * 256 + threadIdx.x;
    int c = (i < N) ? cnt[i] : -1;
    int v = (i < N) ? c + 1 : 0;
    if (i < N) dis[i] = rsqrtf((float)c + 2.0f);
    s[threadIdx.x] = v;
    __syncthreads();
    for (int o = 128; o > 0; o >>= 1) {
        if (threadIdx.x < o) s[threadIdx.x] += s[threadIdx.x + o];
        __syncthreads();
    }
    if (threadIdx.x == 0) bsum[blockIdx.x] = s[0];
}

__global__ void scan_tops(const int* __restrict__ bsum, int* __restrict__ boff, int* __restrict__ rowptrN, int nb) {
    __shared__ int s[256];
    int t = threadIdx.x;
    int v = (t < nb) ? bsum[t] : 0;
    s[t] = v;
    __syncthreads();
    for (int o = 1; o < 256; o <<= 1) {
        int u = (t >= o) ? s[t - o] : 0;
        __syncthreads();
        s[t] += u;
        __syncthreads();
    }
    if (t < nb) boff[t] = s[t] - v;
    if (t == 255) *rowptrN = s[255];
}

__global__ __launch_bounds__(256) void scan_final(const int* __restrict__ cnt, const int* __restrict__ boff,
                                                  const float* __restrict__ dis,
                                                  int* __restrict__ rowptr, int* __restrict__ cursor,
                                                  int2* __restrict__ recs, int N) {
    __shared__ int s[256];
    int t = threadIdx.x;
    int i = blockIdx.x * 256 + t;
    int v = (i < N) ? cnt[i] + 1 : 0;
    s[t] = v;
    __syncthreads();
    for (int o = 1; o < 256; o <<= 1) {
        int u = (t >= o) ? s[t - o] : 0;
        __syncthreads();
        s[t] += u;
        __syncthreads();
    }
    if (i < N) {
        int e = boff[blockIdx.x] + s[t] - v;
        rowptr[i] = e;
        cursor[i] = e + 1;                    // slot e holds the self record
        float d = dis[i];
        int2 r; r.x = i; r.y = f2i(2.0f * d * d);
        recs[e] = r;
    }
}

// XCD-partitioned fill; writes (src, dis[src]*dis[dst]) records
__global__ __launch_bounds__(256) void fill_xcd(const int* __restrict__ ei, int E, int nper,
                                                const float* __restrict__ dis,
                                                int* __restrict__ cursor, int2* __restrict__ recs) {
    int xcd = blockIdx.x & 7;
    int nchunk = gridDim.x >> 3;
    int chunk = blockIdx.x >> 3;
    int csz = (E + nchunk - 1) / nchunk;
    int beg = chunk * csz;
    int end = min(E, beg + csz);
    for (int e = beg + (int)threadIdx.x; e < end; e += 256) {
        int c = ei[E + e];
        if (c / nper == xcd) {
            int r = ei[e];
            int slot = atomicAdd(&cursor[c], 1);
            int2 rec; rec.x = r; rec.y = f2i(dis[r] * dis[c]);
            recs[slot] = rec;
        }
    }
}

// ---------------- aggregation: wave per node, half-wave split, 4 records in flight per half ----------------

__global__ __launch_bounds__(256) void aggregate_rec(const ushortT* __restrict__ h,
                                                     const int* __restrict__ rowptr,
                                                     const int2* __restrict__ recs,
                                                     ushortT* __restrict__ aggb, int N) {
    int n = blockIdx.x * 4 + (threadIdx.x >> 6);
    if (n >= N) return;
    int lane = threadIdx.x & 63;
    int half = lane >> 5, cl = lane & 31;
    int beg = rowptr[n], end = rowptr[n + 1];
    const uint2* h2 = (const uint2*)h;           // 8B units; row stride 32
    float a0 = 0.f, a1 = 0.f, a2 = 0.f, a3 = 0.f;
    float b0 = 0.f, b1 = 0.f, b2 = 0.f, b3 = 0.f;
    float c0 = 0.f, c1 = 0.f, c2 = 0.f, c3 = 0.f;
    float d0 = 0.f, d1 = 0.f, d2 = 0.f, d3 = 0.f;
    int idx = beg + half;
    // main: 4 records per half per iteration (8 rows in flight per wave)
    for (; idx + 6 < end; idx += 8) {
        int2 r0 = recs[idx];
        int2 r1 = recs[idx + 2];
        int2 r2 = recs[idx + 4];
        int2 r3 = recs[idx + 6];
        uint2 v0 = h2[(size_t)r0.x * 32 + cl];
        uint2 v1 = h2[(size_t)r1.x * 32 + cl];
        uint2 v2 = h2[(size_t)r2.x * 32 + cl];
        uint2 v3 = h2[(size_t)r3.x * 32 + cl];
        float n0 = i2f(r0.y), n1 = i2f(r1.y), n2 = i2f(r2.y), n3 = i2f(r3.y);
        a0 = fmaf(n0, bflo(v0.x), a0); a1 = fmaf(n0, bfhi(v0.x), a1);
        a2 = fmaf(n0, bflo(v0.y), a2); a3 = fmaf(n0, bfhi(v0.y), a3);
        b0 = fmaf(n1, bflo(v1.x), b0); b1 = fmaf(n1, bfhi(v1.x), b1);
        b2 = fmaf(n1, bflo(v1.y), b2); b3 = fmaf(n1, bfhi(v1.y), b3);
        c0 = fmaf(n2, bflo(v2.x), c0); c1 = fmaf(n2, bfhi(v2.x), c1);
        c2 = fmaf(n2, bflo(v2.y), c2); c3 = fmaf(n2, bfhi(v2.y), c3);
        d0 = fmaf(n3, bflo(v3.x), d0); d1 = fmaf(n3, bfhi(v3.x), d1);
        d2 = fmaf(n3, bflo(v3.y), d2); d3 = fmaf(n3, bfhi(v3.y), d3);
    }
    // tail: up to 3 leftover records per half
    for (; idx < end; idx += 2) {
        int2 r0 = recs[idx];
        uint2 v0 = h2[(size_t)r0.x * 32 + cl];
        float n0 = i2f(r0.y);
        a0 = fmaf(n0, bflo(v0.x), a0); a1 = fmaf(n0, bfhi(v0.x), a1);
        a2 = fmaf(n0, bflo(v0.y), a2); a3 = fmaf(n0, bfhi(v0.y), a3);
    }
    a0 = (a0 + b0) + (c0 + d0);
    a1 = (a1 + b1) + (c1 + d1);
    a2 = (a2 + b2) + (c2 + d2);
    a3 = (a3 + b3) + (c3 + d3);
    a0 += __shfl_xor(a0, 32);
    a1 += __shfl_xor(a1, 32);
    a2 += __shfl_xor(a2, 32);
    a3 += __shfl_xor(a3, 32);
    if (half == 0) {
        uint2 o;
        o.x = pk2(a0, a1);
        o.y = pk2(a2, a3);
        ((uint2*)aggb)[(size_t)n * 32 + cl] = o;
    }
}

// ---------------- BN stats from bf16 (raw sums) ----------------

__global__ __launch_bounds__(256) void stats_bf(const unsigned* __restrict__ v, int totalU,
                                                float* __restrict__ sums) {
    int tid = blockIdx.x * 256 + threadIdx.x;
    int stride = gridDim.x * 256;
    float sx = 0.f, sy = 0.f, qx = 0.f, qy = 0.f;
    for (int i = tid; i < totalU; i += stride) {
        unsigned u = v[i];
        float a = bflo(u), b = bfhi(u);
        sx += a; sy += b;
        qx = fmaf(a, a, qx); qy = fmaf(b, b, qy);
    }
    __shared__ float l0[256], l1[256], l2[256], l3[256];
    int t = threadIdx.x;
    l0[t] = sx; l1[t] = sy; l2[t] = qx; l3[t] = qy;
    __syncthreads();
    if (t < 64) {
        sx = (l0[t] + l0[t + 64]) + (l0[t + 128] + l0[t + 192]);
        sy = (l1[t] + l1[t + 64]) + (l1[t + 128] + l1[t + 192]);
        qx = (l2[t] + l2[t + 64]) + (l2[t + 128] + l2[t + 192]);
        qy = (l3[t] + l3[t + 64]) + (l3[t + 128] + l3[t + 192]);
        atomicAdd(&sums[2 * t], sx);
        atomicAdd(&sums[2 * t + 1], sy);
        atomicAdd(&sums[128 + 2 * t], qx);
        atomicAdd(&sums[128 + 2 * t + 1], qy);
    }
}

// ---------------- GEMM1 fused: x1 = relu(bn0(agg)) + proj (written out), h = x1 @ W1, LDS epilogue ----------------

__global__ __launch_bounds__(512) void mgemm1_fused(const uint4* __restrict__ aggb,
                                                    const uint4* __restrict__ projb,
                                                    const float* __restrict__ stats,
                                                    const float* __restrict__ g,
                                                    const float* __restrict__ be,
                                                    const ushortT* __restrict__ Wt1,
                                                    ushortT* __restrict__ O,
                                                    uint4* __restrict__ x1b,
                                                    int N) {
    __shared__ __align__(16) ushortT S[17408];
    __shared__ float sc[128], sh[128];
    int tid = threadIdx.x;
    int brow = blockIdx.x * 128;

    if (tid < 128) {
        float mean = stats[tid] / (float)N;
        float var = stats[128 + tid] / (float)N - mean * mean;
        float inv = rsqrtf(var + EPS);
        float s = g[tid] * inv;
        sc[tid] = s;
        sh[tid] = be[tid] - mean * s;
    }
    __syncthreads();

#pragma unroll
    for (int i = 0; i < 4; ++i) {
        int idx = i * 512 + tid;
        int row = idx >> 4, q = idx & 15;
        int gr = brow + row;
        uint4 a = make_uint4(0u, 0u, 0u, 0u), p = a;
        if (gr < N) {
            size_t gidx = (size_t)gr * 16 + q;
            a = aggb[gidx];
            p = projb[gidx];
        }
        int ch = q * 8;
        float v0 = fmaxf(fmaf(bflo(a.x), sc[ch + 0], sh[ch + 0]), 0.f) + bflo(p.x);
        float v1 = fmaxf(fmaf(bfhi(a.x), sc[ch + 1], sh[ch + 1]), 0.f) + bfhi(p.x);
        float v2 = fmaxf(fmaf(bflo(a.y), sc[ch + 2], sh[ch + 2]), 0.f) + bflo(p.y);
        float v3 = fmaxf(fmaf(bfhi(a.y), sc[ch + 3], sh[ch + 3]), 0.f) + bfhi(p.y);
        float v4 = fmaxf(fmaf(bflo(a.z), sc[ch + 4], sh[ch + 4]), 0.f) + bflo(p.z);
        float v5 = fmaxf(fmaf(bfhi(a.z), sc[ch + 5], sh[ch + 5]), 0.f) + bfhi(p.z);
        float v6 = fmaxf(fmaf(bflo(a.w), sc[ch + 6], sh[ch + 6]), 0.f) + bflo(p.w);
        float v7 = fmaxf(fmaf(bfhi(a.w), sc[ch + 7], sh[ch + 7]), 0.f) + bfhi(p.w);
        uint4 pv;
        pv.x = pk2(v0, v1);
        pv.y = pk2(v2, v3);
        pv.z = pk2(v4, v5);
        pv.w = pk2(v6, v7);
        *(uint4*)&S[row * 136 + q * 8] = pv;
        if (gr < N) x1b[(size_t)gr * 16 + q] = pv;
    }
    __syncthreads();

    int w = tid >> 6, lane = tid & 63;
    int lm = lane & 15, lk = lane >> 4;
    int rh = (w >> 2) * 64;
    int colbase = (w & 3) * 32;

    bf16x8 breg[2][4];
#pragma unroll
    for (int nt = 0; nt < 2; ++nt)
#pragma unroll
        for (int ks = 0; ks < 4; ++ks)
            breg[nt][ks] = *(const bf16x8*)&Wt1[(size_t)(colbase + nt * 16 + lm) * H + ks * 32 + lk * 8];

    f32x4 acc[4][2];
#pragma unroll
    for (int mt = 0; mt < 4; ++mt)
#pragma unroll
        for (int nt = 0; nt < 2; ++nt) acc[mt][nt] = (f32x4)0.f;

#pragma unroll
    for (int ks = 0; ks < 4; ++ks) {
        bf16x8 af[4];
#pragma unroll
        for (int mt = 0; mt < 4; ++mt)
            af[mt] = *(const bf16x8*)&S[(rh + mt * 16 + lm) * 136 + ks * 32 + lk * 8];
#pragma unroll
        for (int nt = 0; nt < 2; ++nt)
#pragma unroll
            for (int mt = 0; mt < 4; ++mt)
                acc[mt][nt] = __builtin_amdgcn_mfma_f32_16x16x32_bf16(af[mt], breg[nt][ks], acc[mt][nt], 0, 0, 0);
    }

    __syncthreads();
#pragma unroll
    for (int mt = 0; mt < 4; ++mt)
#pragma unroll
        for (int nt = 0; nt < 2; ++nt) {
            int col = colbase + nt * 16 + lm;
#pragma unroll
            for (int j = 0; j < 4; ++j) {
                int row = rh + mt * 16 + lk * 4 + j;
                S[row * 136 + col] = f2bf(acc[mt][nt][j]);
            }
        }
    __syncthreads();
#pragma unroll
    for (int i = 0; i < 4; ++i) {
        int idx = i * 512 + tid;
        int row = idx >> 4, colq = idx & 15;
        int gr = brow + row;
        if (gr < N) {
            uint4 v = *(const uint4*)&S[row * 136 + colq * 8];
            *(uint4*)&O[(size_t)gr * 128 + colq * 8] = v;
        }
    }
}

// ---------------- head: out = (relu(bn1(agg)) + x1) @ hW + hb, x2 inline ----------------

__global__ __launch_bounds__(256) void head_fused(const uint4* __restrict__ aggb,
                                                  const uint4* __restrict__ x1b,
                                                  const float* __restrict__ stats,
                                                  const float* __restrict__ g,
                                                  const float* __restrict__ be,
                                                  const ushortT* __restrict__ WtH,
                                                  const float* __restrict__ hb,
                                                  float* __restrict__ out, int N) {
    __shared__ __align__(16) ushortT As[64][136];
    __shared__ __align__(16) ushortT Bs[48][136];
    __shared__ float sc[128], sh[128];

    int tid = threadIdx.x;
    int brow = blockIdx.x * 64;
    int w = tid >> 6, lane = tid & 63;
    int lm = lane & 15, lk = lane >> 4;

    if (tid < 128) {
        float mean = stats[tid] / (float)N;
        float var = stats[128 + tid] / (float)N - mean * mean;
        float inv = rsqrtf(var + EPS);
        float s = g[tid] * inv;
        sc[tid] = s;
        sh[tid] = be[tid] - mean * s;
    }
    if (tid < 192) {
        int row = tid >> 2, q = tid & 3;
        const uint4* src = (const uint4*)&WtH[(size_t)row * H + q * 32];
        uint4 a = src[0], b = src[1], c = src[2], d = src[3];
        uint4* dst = (uint4*)&Bs[row][q * 32];
        dst[0] = a; dst[1] = b; dst[2] = c; dst[3] = d;
    }
    __syncthreads();
#pragma unroll
    for (int k = 0; k < 4; ++k) {
        int idx = k * 256 + tid;
        int row = idx >> 4, colq = idx & 15;
        int gr = brow + row;
        uint4 a = make_uint4(0u, 0u, 0u, 0u), x = a;
        if (gr < N) {
            size_t gidx = (size_t)brow * 16 + idx;
            a = aggb[gidx];
            x = x1b[gidx];
        }
        int ch = colq * 8;
        float v0 = fmaxf(fmaf(bflo(a.x), sc[ch + 0], sh[ch + 0]), 0.f) + bflo(x.x);
        float v1 = fmaxf(fmaf(bfhi(a.x), sc[ch + 1], sh[ch + 1]), 0.f) + bfhi(x.x);
        float v2 = fmaxf(fmaf(bflo(a.y), sc[ch + 2], sh[ch + 2]), 0.f) + bflo(x.y);
        float v3 = fmaxf(fmaf(bfhi(a.y), sc[ch + 3], sh[ch + 3]), 0.f) + bfhi(x.y);
        float v4 = fmaxf(fmaf(bflo(a.z), sc[ch + 4], sh[ch + 4]), 0.f) + bflo(x.z);
        float v5 = fmaxf(fmaf(bfhi(a.z), sc[ch + 5], sh[ch + 5]), 0.f) + bfhi(x.z);
        float v6 = fmaxf(fmaf(bflo(a.w), sc[ch + 6], sh[ch + 6]), 0.f) + bflo(x.w);
        float v7 = fmaxf(fmaf(bfhi(a.w), sc[ch + 7], sh[ch + 7]), 0.f) + bfhi(x.w);
        uint4 pv;
        pv.x = pk2(v0, v1);
        pv.y = pk2(v2, v3);
        pv.z = pk2(v4, v5);
        pv.w = pk2(v6, v7);
        *(uint4*)&As[row][colq * 8] = pv;
    }
    __syncthreads();

    f32x4 acc[3];
#pragma unroll
    for (int nt = 0; nt < 3; ++nt) acc[nt] = (f32x4)0.f;
#pragma unroll
    for (int ks = 0; ks < 4; ++ks) {
        bf16x8 a = *(const bf16x8*)&As[w * 16 + lm][ks * 32 + lk * 8];
#pragma unroll
        for (int nt = 0; nt < 3; ++nt) {
            bf16x8 b = *(const bf16x8*)&Bs[nt * 16 + lm][ks * 32 + lk * 8];
            acc[nt] = __builtin_amdgcn_mfma_f32_16x16x32_bf16(a, b, acc[nt], 0, 0, 0);
        }
    }
#pragma unroll
    for (int nt = 0; nt < 3; ++nt) {
        int col = nt * 16 + lm;
        if (col < OUT_DIM) {
            float bbv = hb[col];
#pragma unroll
            for (int j = 0; j < 4; ++j) {
                int r = brow + w * 16 + lk * 4 + j;
                if (r < N) out[(size_t)r * OUT_DIM + col] = acc[nt][j] + bbv;
            }
        }
    }
}

// ---------------- launch ----------------

extern "C" void kernel_launch(void* const* d_in, const int* in_sizes, int n_in,
                              void* d_out, int out_size, void* d_ws, size_t ws_size,
                              hipStream_t stream) {
    const float* x   = (const float*)d_in[0];
    const int*   ei  = (const int*)d_in[1];
    const float* W0  = (const float*)d_in[2];
    // d_in[3] = b0: cancels in BatchNorm
    const float* g0  = (const float*)d_in[4];
    const float* be0 = (const float*)d_in[5];
    const float* pW  = (const float*)d_in[6];
    const float* pb  = (const float*)d_in[7];
    const float* W1  = (const float*)d_in[8];
    // d_in[9] = b1: cancels in BatchNorm
    const float* g1  = (const float*)d_in[10];
    const float* be1 = (const float*)d_in[11];
    const float* hW  = (const float*)d_in[12];
    const float* hb  = (const float*)d_in[13];
    float* out = (float*)d_out;

    int N = in_sizes[0] / IN_DIM;
    int E = in_sizes[1] / 2;
    size_t NH = (size_t)N * H;

    // workspace layout (all bf16 intermediates)
    ushortT* hb16   = (ushortT*)d_ws;            // [N,128] conv input h
    ushortT* aggb   = hb16 + NH;                 // [N,128] aggregated
    ushortT* projb  = aggb + NH;                 // [N,128] proj (block0)
    ushortT* x1b    = projb + NH;                // [N,128] x1
    float*   dis    = (float*)(x1b + NH);        // [N]
    int*     cnt    = (int*)(dis + N);           // [N]
    int*     rowptr = cnt + N;                   // [N+1]
    int*     cursor = rowptr + (N + 1);          // [N]
    int2*    recs   = (int2*)(cursor + N);       // [E+N] (8B-aligned)
    float*   stats  = (float*)(recs + (E + N));  // [512]: conv0 then conv1
    ushortT* Wt0    = (ushortT*)(stats + 512);   // [128*256]
    ushortT* WtP    = Wt0 + 128 * 256;           // [128*256]
    ushortT* Wt1    = WtP + 128 * 256;           // [128*128]
    ushortT* WtH    = Wt1 + 128 * 128;           // [48*128]
    int*     bsum   = (int*)(WtH + 48 * 128);    // [256]
    int*     boff   = bsum + 256;                // [256]
    float*   stats0 = stats;
    float*   stats1 = stats + 256;

    int nb = (N + 255) / 256;
    int g64 = (N + 63) / 64;
    int g128 = (N + 127) / 128;
    int gAgg = (N + 3) / 4;
    int nper = (N + 7) / 8;
    int gemmBlocks = ((g128 + 7) / 8) * 16;      // XCD-paired: 16 blocks per 8 tiles
    const int CNT_BLOCKS = 1024;                 // count role blocks (multiple of 8)

    // prep (weights + zero cnt/stats)
    prep_weights<<<196, 256, 0, stream>>>(W0, pW, W1, hW, Wt0, WtP, Wt1, WtH, cnt, stats, N);

    // GEMM0 (BM=128, XCD-paired single-mat blocks) + degree count in one dispatch
    gemm0_count<<<gemmBlocks + CNT_BLOCKS, 512, 0, stream>>>(x, Wt0, WtP, pb, hb16, projb,
                                                             ei, cnt, N, E, nper,
                                                             gemmBlocks, g128);

    // CSR offsets + records
    scan_block_sum<<<nb, 256, 0, stream>>>(cnt, bsum, dis, N);
    scan_tops<<<1, 256, 0, stream>>>(bsum, boff, &rowptr[N], nb);
    scan_final<<<nb, 256, 0, stream>>>(cnt, boff, dis, rowptr, cursor, recs, N);
    fill_xcd<<<2048, 256, 0, stream>>>(ei, E, nper, dis, cursor, recs);

    // block 0
    aggregate_rec<<<gAgg, 256, 0, stream>>>(hb16, rowptr, recs, aggb, N);
    stats_bf<<<256, 256, 0, stream>>>((const unsigned*)aggb, (int)(NH / 2), stats0);

    // block 1 (x1 = relu(bn0(agg)) + proj fused into GEMM1's staging; x1 also written for head)
    mgemm1_fused<<<g128, 512, 0, stream>>>((const uint4*)aggb, (const uint4*)projb, stats0, g0, be0,
                                           Wt1, hb16, (uint4*)x1b, N);
    aggregate_rec<<<gAgg, 256, 0, stream>>>(hb16, rowptr, recs, aggb, N);
    stats_bf<<<256, 256, 0, stream>>>((const unsigned*)aggb, (int)(NH / 2), stats1);

    // head (x2 computed inline)
    head_fused<<<g64, 256, 0, stream>>>((const uint4*)aggb, (const uint4*)x1b, stats1, g1, be1,
                                        WtH, hb, out, N);
}

// Round 19
// 234.036 us; speedup vs baseline: 1.0662x; 1.0082x over previous
//
#include <hip/hip_runtime.h>

#define H 128
#define IN_DIM 256
#define OUT_DIM 40
#define EPS 1e-5f

typedef unsigned short ushortT;
typedef __attribute__((ext_vector_type(8))) short bf16x8;
typedef __attribute__((ext_vector_type(4))) float f32x4;

static __device__ __forceinline__ ushortT f2bf(float f) {
    union { float f; unsigned u; } v; v.f = f;
    unsigned r = v.u + 0x7FFF + ((v.u >> 16) & 1);   // RNE
    return (ushortT)(r >> 16);
}
static __device__ __forceinline__ unsigned pk2(float a, float b) {
    return (unsigned)f2bf(a) | ((unsigned)f2bf(b) << 16);
}
static __device__ __forceinline__ float bflo(unsigned v) {
    union { unsigned u; float f; } t; t.u = v << 16; return t.f;
}
static __device__ __forceinline__ float bfhi(unsigned v) {
    union { unsigned u; float f; } t; t.u = v & 0xFFFF0000u; return t.f;
}
static __device__ __forceinline__ float i2f(int v) {
    union { int i; float f; } t; t.i = v; return t.f;
}
static __device__ __forceinline__ int f2i(float v) {
    union { float f; int i; } t; t.f = v; return t.i;
}

// ---------------- weight prep: transpose + bf16 (also zeroes cnt + stats) ----------------

__global__ __launch_bounds__(256) void prep_weights(const float* __restrict__ W0, const float* __restrict__ pW,
                                                    const float* __restrict__ W1, const float* __restrict__ hW,
                                                    ushortT* __restrict__ Wt0, ushortT* __restrict__ WtP,
                                                    ushortT* __restrict__ Wt1, ushortT* __restrict__ WtH,
                                                    int* __restrict__ cnt, float* __restrict__ stats, int N) {
    int i = blockIdx.x * 256 + threadIdx.x;
    if (i < 32768) { int n = i >> 8, k = i & 255; Wt0[i] = f2bf(W0[k * 128 + n]); WtP[i] = f2bf(pW[k * 128 + n]); }
    if (i < 16384) { int n = i >> 7, k = i & 127; Wt1[i] = f2bf(W1[k * 128 + n]); }
    if (i < 6144)  { int n = i >> 7, k = i & 127; WtH[i] = (n < OUT_DIM) ? f2bf(hW[k * OUT_DIM + n]) : (ushortT)0; }
    if (i < N) cnt[i] = 0;
    if (i < 512) stats[i] = 0.f;
}

// ---------------- GEMM0 (BM=128, single-mat, XCD-paired, 4-deep K pipeline) + degree count ----------------
// GEMM role: blocks grouped in 16s; bids [16g,16g+8) = mat0 of tiles 8g..8g+7,
//   bids [16g+8,16g+16) = mat1 of same tiles -> tile's two blocks share bid%8 (same XCD, L2 A-reuse).
// K = 4 chunks of 64, LDS dbuf, loads for chunk k+2 issued before chunk k's MFMA. 1 barrier/chunk.
// blocks [gemmBlocks, ...): XCD-partitioned degree count.

static __device__ __forceinline__ void g4_loads(const float* __restrict__ X, int brow, int kc,
                                                int tid, int N, float4 pf[4]) {
#pragma unroll
    for (int i = 0; i < 4; ++i) {
        int idx = i * 512 + tid;
        int row = idx >> 4, c4 = idx & 15;
        int gr = brow + row;
        pf[i] = make_float4(0.f, 0.f, 0.f, 0.f);
        if (gr < N) pf[i] = *(const float4*)&X[(size_t)gr * IN_DIM + kc * 64 + c4 * 4];
    }
}
static __device__ __forceinline__ void g4_write(ushortT* __restrict__ Sbuf, int tid, const float4 pf[4]) {
#pragma unroll
    for (int i = 0; i < 4; ++i) {
        int idx = i * 512 + tid;
        int row = idx >> 4, c4 = idx & 15;
        uint2 p;
        p.x = pk2(pf[i].x, pf[i].y);
        p.y = pk2(pf[i].z, pf[i].w);
        *(uint2*)&Sbuf[row * 72 + c4 * 4] = p;
    }
}

__global__ __launch_bounds__(512) void gemm0_count(const float* __restrict__ X,
                                                   const ushortT* __restrict__ Wt0,
                                                   const ushortT* __restrict__ WtP,
                                                   const float* __restrict__ pb,
                                                   ushortT* __restrict__ Oh,
                                                   ushortT* __restrict__ Op,
                                                   const int* __restrict__ ei,
                                                   int* __restrict__ cnt,
                                                   int N, int E, int nper,
                                                   int gemmBlocks, int ntiles) {
    __shared__ __align__(16) ushortT S[18432];       // 2 x [128][72] dbuf; reused as C[128][136]
    int tid = threadIdx.x;

    if (blockIdx.x >= gemmBlocks) {
        // ---- count role ----
        int cbid = blockIdx.x - gemmBlocks;
        int xcd = cbid & 7;
        int nchunk = (gridDim.x - gemmBlocks) >> 3;
        int chunk = cbid >> 3;
        int csz = (E + nchunk - 1) / nchunk;
        int beg = chunk * csz;
        int end = min(E, beg + csz);
        for (int e = beg + tid; e < end; e += 512) {
            int c = ei[E + e];
            if (c / nper == xcd) atomicAdd(&cnt[c], 1);
        }
        return;
    }

    // ---- GEMM role (XCD-paired mapping, 4-chunk pipeline) ----
    int gb = blockIdx.x;
    int mat = (gb >> 3) & 1;
    int tile = ((gb >> 4) << 3) | (gb & 7);
    if (tile >= ntiles) return;
    int brow = tile * 128;
    int w = tid >> 6, lane = tid & 63;
    int lm = lane & 15, lk = lane >> 4;
    int rh = (w >> 2) * 64;
    int colbase = (w & 3) * 32;
    const ushortT* Wt = mat ? WtP : Wt0;
    float bb0 = mat ? pb[colbase + lm] : 0.f;
    float bb1 = mat ? pb[colbase + 16 + lm] : 0.f;
    ushortT* O = mat ? Op : Oh;

    f32x4 acc[4][2];
#pragma unroll
    for (int mt = 0; mt < 4; ++mt)
#pragma unroll
        for (int nt = 0; nt < 2; ++nt) acc[mt][nt] = (f32x4)0.f;

    float4 pf[4];
    g4_loads(X, brow, 0, tid, N, pf);
    g4_write(&S[0], tid, pf);
    __syncthreads();                                   // chunk0 staged
    g4_loads(X, brow, 1, tid, N, pf);                  // chunk1 in flight

#pragma unroll
    for (int kc = 0; kc < 4; ++kc) {
        ushortT* Sc = &S[(kc & 1) * 9216];
        // B for this chunk (16 VGPRs)
        bf16x8 breg[2][2];
#pragma unroll
        for (int nt = 0; nt < 2; ++nt)
#pragma unroll
            for (int ks = 0; ks < 2; ++ks)
                breg[nt][ks] = *(const bf16x8*)&Wt[(size_t)(colbase + nt * 16 + lm) * IN_DIM + kc * 64 + ks * 32 + lk * 8];
#pragma unroll
        for (int ks = 0; ks < 2; ++ks) {
            bf16x8 af[4];
#pragma unroll
            for (int mt = 0; mt < 4; ++mt)
                af[mt] = *(const bf16x8*)&Sc[(rh + mt * 16 + lm) * 72 + ks * 32 + lk * 8];
#pragma unroll
            for (int nt = 0; nt < 2; ++nt)
#pragma unroll
                for (int mt = 0; mt < 4; ++mt)
                    acc[mt][nt] = __builtin_amdgcn_mfma_f32_16x16x32_bf16(af[mt], breg[nt][ks], acc[mt][nt], 0, 0, 0);
        }
        if (kc < 3) {
            g4_write(&S[((kc + 1) & 1) * 9216], tid, pf);   // write staged chunk kc+1
            __syncthreads();                                // ready for next mfma
            if (kc < 2) g4_loads(X, brow, kc + 2, tid, N, pf);  // issue chunk kc+2
        }
    }

    __syncthreads();                               // all A reads done; reuse S as C [128][136]
#pragma unroll
    for (int mt = 0; mt < 4; ++mt)
#pragma unroll
        for (int nt = 0; nt < 2; ++nt) {
            int col = colbase + nt * 16 + lm;
            float bb = nt ? bb1 : bb0;
#pragma unroll
            for (int j = 0; j < 4; ++j) {
                int row = rh + mt * 16 + lk * 4 + j;
                S[row * 136 + col] = f2bf(acc[mt][nt][j] + bb);
            }
        }
    __syncthreads();
    // coalesced stores: 2048 uint4 (128 rows x 16 uint4), 4/thread
#pragma unroll
    for (int i = 0; i < 4; ++i) {
        int idx = i * 512 + tid;
        int row = idx >> 4, colq = idx & 15;
        int gr = brow + row;
        if (gr < N) {
            uint4 v = *(const uint4*)&S[row * 136 + colq * 8];
            *(uint4*)&O[(size_t)gr * 128 + colq * 8] = v;
        }
    }
}

// ---------------- scan hierarchy ----------------

__global__ __launch_bounds__(256) void scan_block_sum(const int* __restrict__ cnt, int* __restrict__ bsum,
                                                      float* __restrict__ dis, int N) {
    __shared__ int s[256];
    int i = blockIdx.x * 256 + threadIdx.x;
    int c = (i < N) ? cnt[i] : -1;
    int v = (i < N) ? c + 1 : 0;
    if (i < N) dis[i] = rsqrtf((float)c + 2.0f);
    s[threadIdx.x] = v;
    __syncthreads();
    for (int o = 128; o > 0; o >>= 1) {
        if (threadIdx.x < o) s[threadIdx.x] += s[threadIdx.x + o];
        __syncthreads();
    }
    if (threadIdx.x == 0) bsum[blockIdx.x] = s[0];
}

__global__ void scan_tops(const int* __restrict__ bsum, int* __restrict__ boff, int* __restrict__ rowptrN, int nb) {
    __shared__ int s[256];
    int t = threadIdx.x;
    int v = (t < nb) ? bsum[t] : 0;
    s[t] = v;
    __syncthreads();
    for (int o = 1; o < 256; o <<= 1) {
        int u = (t >= o) ? s[t - o] : 0;
        __syncthreads();
        s[t] += u;
        __syncthreads();
    }
    if (t < nb) boff[t] = s[t] - v;
    if (t == 255) *rowptrN = s[255];
}

__global__ __launch_bounds__(256) void scan_final(const int* __restrict__ cnt, const int* __restrict__ boff,
                                                  const float* __restrict__ dis,
                                                  int* __restrict__ rowptr, int* __restrict__ cursor,
                                                  int2* __restrict__ recs, int N) {
    __shared__ int s[256];
    int t = threadIdx.x;
    int i = blockIdx.x * 256 + t;
    int v = (i < N) ? cnt[i] + 1 : 0;
    s[t] = v;
    __syncthreads();
    for (int o = 1; o < 256; o <<= 1) {
        int u = (t >= o) ? s[t - o] : 0;
        __syncthreads();
        s[t] += u;
        __syncthreads();
    }
    if (i < N) {
        int e = boff[blockIdx.x] + s[t] - v;
        rowptr[i] = e;
        cursor[i] = e + 1;                    // slot e holds the self record
        float d = dis[i];
        int2 r; r.x = i; r.y = f2i(2.0f * d * d);
        recs[e] = r;
    }
}

// XCD-partitioned fill; writes (src, dis[src]*dis[dst]) records
__global__ __launch_bounds__(256) void fill_xcd(const int* __restrict__ ei, int E, int nper,
                                                const float* __restrict__ dis,
                                                int* __restrict__ cursor, int2* __restrict__ recs) {
    int xcd = blockIdx.x & 7;
    int nchunk = gridDim.x >> 3;
    int chunk = blockIdx.x >> 3;
    int csz = (E + nchunk - 1) / nchunk;
    int beg = chunk * csz;
    int end = min(E, beg + csz);
    for (int e = beg + (int)threadIdx.x; e < end; e += 256) {
        int c = ei[E + e];
        if (c / nper == xcd) {
            int r = ei[e];
            int slot = atomicAdd(&cursor[c], 1);
            int2 rec; rec.x = r; rec.y = f2i(dis[r] * dis[c]);
            recs[slot] = rec;
        }
    }
}

// ---------------- aggregation: wave per node, half-wave split, 4 records in flight per half ----------------

__global__ __launch_bounds__(256) void aggregate_rec(const ushortT* __restrict__ h,
                                                     const int* __restrict__ rowptr,
                                                     const int2* __restrict__ recs,
                                                     ushortT* __restrict__ aggb, int N) {
    int n = blockIdx.x * 4 + (threadIdx.x >> 6);
    if (n >= N) return;
    int lane = threadIdx.x & 63;
    int half = lane >> 5, cl = lane & 31;
    int beg = rowptr[n], end = rowptr[n + 1];
    const uint2* h2 = (const uint2*)h;           // 8B units; row stride 32
    float a0 = 0.f, a1 = 0.f, a2 = 0.f, a3 = 0.f;
    float b0 = 0.f, b1 = 0.f, b2 = 0.f, b3 = 0.f;
    float c0 = 0.f, c1 = 0.f, c2 = 0.f, c3 = 0.f;
    float d0 = 0.f, d1 = 0.f, d2 = 0.f, d3 = 0.f;
    int idx = beg + half;
    // main: 4 records per half per iteration (8 rows in flight per wave)
    for (; idx + 6 < end; idx += 8) {
        int2 r0 = recs[idx];
        int2 r1 = recs[idx + 2];
        int2 r2 = recs[idx + 4];
        int2 r3 = recs[idx + 6];
        uint2 v0 = h2[(size_t)r0.x * 32 + cl];
        uint2 v1 = h2[(size_t)r1.x * 32 + cl];
        uint2 v2 = h2[(size_t)r2.x * 32 + cl];
        uint2 v3 = h2[(size_t)r3.x * 32 + cl];
        float n0 = i2f(r0.y), n1 = i2f(r1.y), n2 = i2f(r2.y), n3 = i2f(r3.y);
        a0 = fmaf(n0, bflo(v0.x), a0); a1 = fmaf(n0, bfhi(v0.x), a1);
        a2 = fmaf(n0, bflo(v0.y), a2); a3 = fmaf(n0, bfhi(v0.y), a3);
        b0 = fmaf(n1, bflo(v1.x), b0); b1 = fmaf(n1, bfhi(v1.x), b1);
        b2 = fmaf(n1, bflo(v1.y), b2); b3 = fmaf(n1, bfhi(v1.y), b3);
        c0 = fmaf(n2, bflo(v2.x), c0); c1 = fmaf(n2, bfhi(v2.x), c1);
        c2 = fmaf(n2, bflo(v2.y), c2); c3 = fmaf(n2, bfhi(v2.y), c3);
        d0 = fmaf(n3, bflo(v3.x), d0); d1 = fmaf(n3, bfhi(v3.x), d1);
        d2 = fmaf(n3, bflo(v3.y), d2); d3 = fmaf(n3, bfhi(v3.y), d3);
    }
    // tail: up to 3 leftover records per half
    for (; idx < end; idx += 2) {
        int2 r0 = recs[idx];
        uint2 v0 = h2[(size_t)r0.x * 32 + cl];
        float n0 = i2f(r0.y);
        a0 = fmaf(n0, bflo(v0.x), a0); a1 = fmaf(n0, bfhi(v0.x), a1);
        a2 = fmaf(n0, bflo(v0.y), a2); a3 = fmaf(n0, bfhi(v0.y), a3);
    }
    a0 = (a0 + b0) + (c0 + d0);
    a1 = (a1 + b1) + (c1 + d1);
    a2 = (a2 + b2) + (c2 + d2);
    a3 = (a3 + b3) + (c3 + d3);
    a0 += __shfl_xor(a0, 32);
    a1 += __shfl_xor(a1, 32);
    a2 += __shfl_xor(a2, 32);
    a3 += __shfl_xor(a3, 32);
    if (half == 0) {
        uint2 o;
        o.x = pk2(a0, a1);
        o.y = pk2(a2, a3);
        ((uint2*)aggb)[(size_t)n * 32 + cl] = o;
    }
}

// ---------------- BN stats from bf16 (raw sums) ----------------

__global__ __launch_bounds__(256) void stats_bf(const unsigned* __restrict__ v, int totalU,
                                                float* __restrict__ sums) {
    int tid = blockIdx.x * 256 + threadIdx.x;
    int stride = gridDim.x * 256;
    float sx = 0.f, sy = 0.f, qx = 0.f, qy = 0.f;
    for (int i = tid; i < totalU; i += stride) {
        unsigned u = v[i];
        float a = bflo(u), b = bfhi(u);
        sx += a; sy += b;
        qx = fmaf(a, a, qx); qy = fmaf(b, b, qy);
    }
    __shared__ float l0[256], l1[256], l2[256], l3[256];
    int t = threadIdx.x;
    l0[t] = sx; l1[t] = sy; l2[t] = qx; l3[t] = qy;
    __syncthreads();
    if (t < 64) {
        sx = (l0[t] + l0[t + 64]) + (l0[t + 128] + l0[t + 192]);
        sy = (l1[t] + l1[t + 64]) + (l1[t + 128] + l1[t + 192]);
        qx = (l2[t] + l2[t + 64]) + (l2[t + 128] + l2[t + 192]);
        qy = (l3[t] + l3[t + 64]) + (l3[t + 128] + l3[t + 192]);
        atomicAdd(&sums[2 * t], sx);
        atomicAdd(&sums[2 * t + 1], sy);
        atomicAdd(&sums[128 + 2 * t], qx);
        atomicAdd(&sums[128 + 2 * t + 1], qy);
    }
}

// ---------------- GEMM1 fused: x1 = relu(bn0(agg)) + proj (written out), h = x1 @ W1, LDS epilogue ----------------

__global__ __launch_bounds__(512) void mgemm1_fused(const uint4* __restrict__ aggb,
                                                    const uint4* __restrict__ projb,
                                                    const float* __restrict__ stats,
                                                    const float* __restrict__ g,
                                                    const float* __restrict__ be,
                                                    const ushortT* __restrict__ Wt1,
                                                    ushortT* __restrict__ O,
                                                    uint4* __restrict__ x1b,
                                                    int N) {
    __shared__ __align__(16) ushortT S[17408];
    __shared__ float sc[128], sh[128];
    int tid = threadIdx.x;
    int brow = blockIdx.x * 128;

    if (tid < 128) {
        float mean = stats[tid] / (float)N;
        float var = stats[128 + tid] / (float)N - mean * mean;
        float inv = rsqrtf(var + EPS);
        float s = g[tid] * inv;
        sc[tid] = s;
        sh[tid] = be[tid] - mean * s;
    }
    __syncthreads();

#pragma unroll
    for (int i = 0; i < 4; ++i) {
        int idx = i * 512 + tid;
        int row = idx >> 4, q = idx & 15;
        int gr = brow + row;
        uint4 a = make_uint4(0u, 0u, 0u, 0u), p = a;
        if (gr < N) {
            size_t gidx = (size_t)gr * 16 + q;
            a = aggb[gidx];
            p = projb[gidx];
        }
        int ch = q * 8;
        float v0 = fmaxf(fmaf(bflo(a.x), sc[ch + 0], sh[ch + 0]), 0.f) + bflo(p.x);
        float v1 = fmaxf(fmaf(bfhi(a.x), sc[ch + 1], sh[ch + 1]), 0.f) + bfhi(p.x);
        float v2 = fmaxf(fmaf(bflo(a.y), sc[ch + 2], sh[ch + 2]), 0.f) + bflo(p.y);
        float v3 = fmaxf(fmaf(bfhi(a.y), sc[ch + 3], sh[ch + 3]), 0.f) + bfhi(p.y);
        float v4 = fmaxf(fmaf(bflo(a.z), sc[ch + 4], sh[ch + 4]), 0.f) + bflo(p.z);
        float v5 = fmaxf(fmaf(bfhi(a.z), sc[ch + 5], sh[ch + 5]), 0.f) + bfhi(p.z);
        float v6 = fmaxf(fmaf(bflo(a.w), sc[ch + 6], sh[ch + 6]), 0.f) + bflo(p.w);
        float v7 = fmaxf(fmaf(bfhi(a.w), sc[ch + 7], sh[ch + 7]), 0.f) + bfhi(p.w);
        uint4 pv;
        pv.x = pk2(v0, v1);
        pv.y = pk2(v2, v3);
        pv.z = pk2(v4, v5);
        pv.w = pk2(v6, v7);
        *(uint4*)&S[row * 136 + q * 8] = pv;
        if (gr < N) x1b[(size_t)gr * 16 + q] = pv;
    }
    __syncthreads();

    int w = tid >> 6, lane = tid & 63;
    int lm = lane & 15, lk = lane >> 4;
    int rh = (w >> 2) * 64;
    int colbase = (w & 3) * 32;

    bf16x8 breg[2][4];
#pragma unroll
    for (int nt = 0; nt < 2; ++nt)
#pragma unroll
        for (int ks = 0; ks < 4; ++ks)
            breg[nt][ks] = *(const bf16x8*)&Wt1[(size_t)(colbase + nt * 16 + lm) * H + ks * 32 + lk * 8];

    f32x4 acc[4][2];
#pragma unroll
    for (int mt = 0; mt < 4; ++mt)
#pragma unroll
        for (int nt = 0; nt < 2; ++nt) acc[mt][nt] = (f32x4)0.f;

#pragma unroll
    for (int ks = 0; ks < 4; ++ks) {
        bf16x8 af[4];
#pragma unroll
        for (int mt = 0; mt < 4; ++mt)
            af[mt] = *(const bf16x8*)&S[(rh + mt * 16 + lm) * 136 + ks * 32 + lk * 8];
#pragma unroll
        for (int nt = 0; nt < 2; ++nt)
#pragma unroll
            for (int mt = 0; mt < 4; ++mt)
                acc[mt][nt] = __builtin_amdgcn_mfma_f32_16x16x32_bf16(af[mt], breg[nt][ks], acc[mt][nt], 0, 0, 0);
    }

    __syncthreads();
#pragma unroll
    for (int mt = 0; mt < 4; ++mt)
#pragma unroll
        for (int nt = 0; nt < 2; ++nt) {
            int col = colbase + nt * 16 + lm;
#pragma unroll
            for (int j = 0; j < 4; ++j) {
                int row = rh + mt * 16 + lk * 4 + j;
                S[row * 136 + col] = f2bf(acc[mt][nt][j]);
            }
        }
    __syncthreads();
#pragma unroll
    for (int i = 0; i < 4; ++i) {
        int idx = i * 512 + tid;
        int row = idx >> 4, colq = idx & 15;
        int gr = brow + row;
        if (gr < N) {
            uint4 v = *(const uint4*)&S[row * 136 + colq * 8];
            *(uint4*)&O[(size_t)gr * 128 + colq * 8] = v;
        }
    }
}

// ---------------- head: out = (relu(bn1(agg)) + x1) @ hW + hb, x2 inline ----------------

__global__ __launch_bounds__(256) void head_fused(const uint4* __restrict__ aggb,
                                                  const uint4* __restrict__ x1b,
                                                  const float* __restrict__ stats,
                                                  const float* __restrict__ g,
                                                  const float* __restrict__ be,
                                                  const ushortT* __restrict__ WtH,
                                                  const float* __restrict__ hb,
                                                  float* __restrict__ out, int N) {
    __shared__ __align__(16) ushortT As[64][136];
    __shared__ __align__(16) ushortT Bs[48][136];
    __shared__ float sc[128], sh[128];

    int tid = threadIdx.x;
    int brow = blockIdx.x * 64;
    int w = tid >> 6, lane = tid & 63;
    int lm = lane & 15, lk = lane >> 4;

    if (tid < 128) {
        float mean = stats[tid] / (float)N;
        float var = stats[128 + tid] / (float)N - mean * mean;
        float inv = rsqrtf(var + EPS);
        float s = g[tid] * inv;
        sc[tid] = s;
        sh[tid] = be[tid] - mean * s;
    }
    if (tid < 192) {
        int row = tid >> 2, q = tid & 3;
        const uint4* src = (const uint4*)&WtH[(size_t)row * H + q * 32];
        uint4 a = src[0], b = src[1], c = src[2], d = src[3];
        uint4* dst = (uint4*)&Bs[row][q * 32];
        dst[0] = a; dst[1] = b; dst[2] = c; dst[3] = d;
    }
    __syncthreads();
#pragma unroll
    for (int k = 0; k < 4; ++k) {
        int idx = k * 256 + tid;
        int row = idx >> 4, colq = idx & 15;
        int gr = brow + row;
        uint4 a = make_uint4(0u, 0u, 0u, 0u), x = a;
        if (gr < N) {
            size_t gidx = (size_t)brow * 16 + idx;
            a = aggb[gidx];
            x = x1b[gidx];
        }
        int ch = colq * 8;
        float v0 = fmaxf(fmaf(bflo(a.x), sc[ch + 0], sh[ch + 0]), 0.f) + bflo(x.x);
        float v1 = fmaxf(fmaf(bfhi(a.x), sc[ch + 1], sh[ch + 1]), 0.f) + bfhi(x.x);
        float v2 = fmaxf(fmaf(bflo(a.y), sc[ch + 2], sh[ch + 2]), 0.f) + bflo(x.y);
        float v3 = fmaxf(fmaf(bfhi(a.y), sc[ch + 3], sh[ch + 3]), 0.f) + bfhi(x.y);
        float v4 = fmaxf(fmaf(bflo(a.z), sc[ch + 4], sh[ch + 4]), 0.f) + bflo(x.z);
        float v5 = fmaxf(fmaf(bfhi(a.z), sc[ch + 5], sh[ch + 5]), 0.f) + bfhi(x.z);
        float v6 = fmaxf(fmaf(bflo(a.w), sc[ch + 6], sh[ch + 6]), 0.f) + bflo(x.w);
        float v7 = fmaxf(fmaf(bfhi(a.w), sc[ch + 7], sh[ch + 7]), 0.f) + bfhi(x.w);
        uint4 pv;
        pv.x = pk2(v0, v1);
        pv.y = pk2(v2, v3);
        pv.z = pk2(v4, v5);
        pv.w = pk2(v6, v7);
        *(uint4*)&As[row][colq * 8] = pv;
    }
    __syncthreads();

    f32x4 acc[3];
#pragma unroll
    for (int nt = 0; nt < 3; ++nt) acc[nt] = (f32x4)0.f;
#pragma unroll
    for (int ks = 0; ks < 4; ++ks) {
        bf16x8 a = *(const bf16x8*)&As[w * 16 + lm][ks * 32 + lk * 8];
#pragma unroll
        for (int nt = 0; nt < 3; ++nt) {
            bf16x8 b = *(const bf16x8*)&Bs[nt * 16 + lm][ks * 32 + lk * 8];
            acc[nt] = __builtin_amdgcn_mfma_f32_16x16x32_bf16(a, b, acc[nt], 0, 0, 0);
        }
    }
#pragma unroll
    for (int nt = 0; nt < 3; ++nt) {
        int col = nt * 16 + lm;
        if (col < OUT_DIM) {
            float bbv = hb[col];
#pragma unroll
            for (int j = 0; j < 4; ++j) {
                int r = brow + w * 16 + lk * 4 + j;
                if (r < N) out[(size_t)r * OUT_DIM + col] = acc[nt][j] + bbv;
            }
        }
    }
}

// ---------------- launch ----------------

extern "C" void kernel_launch(void* const* d_in, const int* in_sizes, int n_in,
                              void* d_out, int out_size, void* d_ws, size_t ws_size,
                              hipStream_t stream) {
    const float* x   = (const float*)d_in[0];
    const int*   ei  = (const int*)d_in[1];
    const float* W0  = (const float*)d_in[2];
    // d_in[3] = b0: cancels in BatchNorm
    const float* g0  = (const float*)d_in[4];
    const float* be0 = (const float*)d_in[5];
    const float* pW  = (const float*)d_in[6];
    const float* pb  = (const float*)d_in[7];
    const float* W1  = (const float*)d_in[8];
    // d_in[9] = b1: cancels in BatchNorm
    const float* g1  = (const float*)d_in[10];
    const float* be1 = (const float*)d_in[11];
    const float* hW  = (const float*)d_in[12];
    const float* hb  = (const float*)d_in[13];
    float* out = (float*)d_out;

    int N = in_sizes[0] / IN_DIM;
    int E = in_sizes[1] / 2;
    size_t NH = (size_t)N * H;

    // workspace layout (all bf16 intermediates)
    ushortT* hb16   = (ushortT*)d_ws;            // [N,128] conv input h
    ushortT* aggb   = hb16 + NH;                 // [N,128] aggregated
    ushortT* projb  = aggb + NH;                 // [N,128] proj (block0)
    ushortT* x1b    = projb + NH;                // [N,128] x1
    float*   dis    = (float*)(x1b + NH);        // [N]
    int*     cnt    = (int*)(dis + N);           // [N]
    int*     rowptr = cnt + N;                   // [N+1]
    int*     cursor = rowptr + (N + 1);          // [N]
    int2*    recs   = (int2*)(cursor + N);       // [E+N] (8B-aligned)
    float*   stats  = (float*)(recs + (E + N));  // [512]: conv0 then conv1
    ushortT* Wt0    = (ushortT*)(stats + 512);   // [128*256]
    ushortT* WtP    = Wt0 + 128 * 256;           // [128*256]
    ushortT* Wt1    = WtP + 128 * 256;           // [128*128]
    ushortT* WtH    = Wt1 + 128 * 128;           // [48*128]
    int*     bsum   = (int*)(WtH + 48 * 128);    // [256]
    int*     boff   = bsum + 256;                // [256]
    float*   stats0 = stats;
    float*   stats1 = stats + 256;

    int nb = (N + 255) / 256;
    int g64 = (N + 63) / 64;
    int g128 = (N + 127) / 128;
    int gAgg = (N + 3) / 4;
    int nper = (N + 7) / 8;
    int gemmBlocks = ((g128 + 7) / 8) * 16;      // XCD-paired: 16 blocks per 8 tiles
    const int CNT_BLOCKS = 1024;                 // count role blocks (multiple of 8)

    // prep (weights + zero cnt/stats)
    prep_weights<<<196, 256, 0, stream>>>(W0, pW, W1, hW, Wt0, WtP, Wt1, WtH, cnt, stats, N);

    // GEMM0 (BM=128, XCD-paired, 4-deep K pipeline) + degree count in one dispatch
    gemm0_count<<<gemmBlocks + CNT_BLOCKS, 512, 0, stream>>>(x, Wt0, WtP, pb, hb16, projb,
                                                             ei, cnt, N, E, nper,
                                                             gemmBlocks, g128);

    // CSR offsets + records
    scan_block_sum<<<nb, 256, 0, stream>>>(cnt, bsum, dis, N);
    scan_tops<<<1, 256, 0, stream>>>(bsum, boff, &rowptr[N], nb);
    scan_final<<<nb, 256, 0, stream>>>(cnt, boff, dis, rowptr, cursor, recs, N);
    fill_xcd<<<2048, 256, 0, stream>>>(ei, E, nper, dis, cursor, recs);

    // block 0
    aggregate_rec<<<gAgg, 256, 0, stream>>>(hb16, rowptr, recs, aggb, N);
    stats_bf<<<256, 256, 0, stream>>>((const unsigned*)aggb, (int)(NH / 2), stats0);

    // block 1 (x1 = relu(bn0(agg)) + proj fused into GEMM1's staging; x1 also written for head)
    mgemm1_fused<<<g128, 512, 0, stream>>>((const uint4*)aggb, (const uint4*)projb, stats0, g0, be0,
                                           Wt1, hb16, (uint4*)x1b, N);
    aggregate_rec<<<gAgg, 256, 0, stream>>>(hb16, rowptr, recs, aggb, N);
    stats_bf<<<256, 256, 0, stream>>>((const unsigned*)aggb, (int)(NH / 2), stats1);

    // head (x2 computed inline)
    head_fused<<<g64, 256, 0, stream>>>((const uint4*)aggb, (const uint4*)x1b, stats1, g1, be1,
                                        WtH, hb, out, N);
}

// Round 20
// 232.062 us; speedup vs baseline: 1.0753x; 1.0085x over previous
//
#include <hip/hip_runtime.h>

#define H 128
#define IN_DIM 256
#define OUT_DIM 40
#define EPS 1e-5f

typedef unsigned short ushortT;
typedef __attribute__((ext_vector_type(8))) short bf16x8;
typedef __attribute__((ext_vector_type(4))) float f32x4;

static __device__ __forceinline__ ushortT f2bf(float f) {
    union { float f; unsigned u; } v; v.f = f;
    unsigned r = v.u + 0x7FFF + ((v.u >> 16) & 1);   // RNE
    return (ushortT)(r >> 16);
}
static __device__ __forceinline__ unsigned pk2(float a, float b) {
    return (unsigned)f2bf(a) | ((unsigned)f2bf(b) << 16);
}
static __device__ __forceinline__ float bflo(unsigned v) {
    union { unsigned u; float f; } t; t.u = v << 16; return t.f;
}
static __device__ __forceinline__ float bfhi(unsigned v) {
    union { unsigned u; float f; } t; t.u = v & 0xFFFF0000u; return t.f;
}
static __device__ __forceinline__ float i2f(int v) {
    union { int i; float f; } t; t.i = v; return t.f;
}
static __device__ __forceinline__ int f2i(float v) {
    union { float f; int i; } t; t.f = v; return t.i;
}

// ---------------- weight prep: transpose + bf16 (also zeroes cnt + stats) ----------------

__global__ __launch_bounds__(256) void prep_weights(const float* __restrict__ W0, const float* __restrict__ pW,
                                                    const float* __restrict__ W1, const float* __restrict__ hW,
                                                    ushortT* __restrict__ Wt0, ushortT* __restrict__ WtP,
                                                    ushortT* __restrict__ Wt1, ushortT* __restrict__ WtH,
                                                    int* __restrict__ cnt, float* __restrict__ stats, int N) {
    int i = blockIdx.x * 256 + threadIdx.x;
    if (i < 32768) { int n = i >> 8, k = i & 255; Wt0[i] = f2bf(W0[k * 128 + n]); WtP[i] = f2bf(pW[k * 128 + n]); }
    if (i < 16384) { int n = i >> 7, k = i & 127; Wt1[i] = f2bf(W1[k * 128 + n]); }
    if (i < 6144)  { int n = i >> 7, k = i & 127; WtH[i] = (n < OUT_DIM) ? f2bf(hW[k * OUT_DIM + n]) : (ushortT)0; }
    if (i < N) cnt[i] = 0;
    if (i < 512) stats[i] = 0.f;
}

// ---------------- GEMM0 (BM=128, single-mat, XCD-paired, 4-deep K pipeline) + degree count ----------------
// GEMM role: blocks grouped in 16s; bids [16g,16g+8) = mat0 of tiles 8g..8g+7,
//   bids [16g+8,16g+16) = mat1 of same tiles -> tile's two blocks share bid%8 (same XCD, L2 A-reuse).
// K = 4 chunks of 64, LDS dbuf, loads for chunk k+2 issued before chunk k's MFMA. 1 barrier/chunk.
// blocks [gemmBlocks, ...): disjoint-chunk plain-atomic degree count (atomics resolve at shared LLC).

static __device__ __forceinline__ void g4_loads(const float* __restrict__ X, int brow, int kc,
                                                int tid, int N, float4 pf[4]) {
#pragma unroll
    for (int i = 0; i < 4; ++i) {
        int idx = i * 512 + tid;
        int row = idx >> 4, c4 = idx & 15;
        int gr = brow + row;
        pf[i] = make_float4(0.f, 0.f, 0.f, 0.f);
        if (gr < N) pf[i] = *(const float4*)&X[(size_t)gr * IN_DIM + kc * 64 + c4 * 4];
    }
}
static __device__ __forceinline__ void g4_write(ushortT* __restrict__ Sbuf, int tid, const float4 pf[4]) {
#pragma unroll
    for (int i = 0; i < 4; ++i) {
        int idx = i * 512 + tid;
        int row = idx >> 4, c4 = idx & 15;
        uint2 p;
        p.x = pk2(pf[i].x, pf[i].y);
        p.y = pk2(pf[i].z, pf[i].w);
        *(uint2*)&Sbuf[row * 72 + c4 * 4] = p;
    }
}

__global__ __launch_bounds__(512) void gemm0_count(const float* __restrict__ X,
                                                   const ushortT* __restrict__ Wt0,
                                                   const ushortT* __restrict__ WtP,
                                                   const float* __restrict__ pb,
                                                   ushortT* __restrict__ Oh,
                                                   ushortT* __restrict__ Op,
                                                   const int* __restrict__ ei,
                                                   int* __restrict__ cnt,
                                                   int N, int E,
                                                   int gemmBlocks, int ntiles) {
    __shared__ __align__(16) ushortT S[18432];       // 2 x [128][72] dbuf; reused as C[128][136]
    int tid = threadIdx.x;

    if (blockIdx.x >= gemmBlocks) {
        // ---- count role: disjoint chunks, plain atomics (each edge read once) ----
        int cbid = blockIdx.x - gemmBlocks;
        int nblk = gridDim.x - gemmBlocks;
        int csz = (E + nblk - 1) / nblk;
        int beg = cbid * csz;
        int end = min(E, beg + csz);
        for (int e = beg + tid; e < end; e += 512) {
            atomicAdd(&cnt[ei[E + e]], 1);
        }
        return;
    }

    // ---- GEMM role (XCD-paired mapping, 4-chunk pipeline) ----
    int gb = blockIdx.x;
    int mat = (gb >> 3) & 1;
    int tile = ((gb >> 4) << 3) | (gb & 7);
    if (tile >= ntiles) return;
    int brow = tile * 128;
    int w = tid >> 6, lane = tid & 63;
    int lm = lane & 15, lk = lane >> 4;
    int rh = (w >> 2) * 64;
    int colbase = (w & 3) * 32;
    const ushortT* Wt = mat ? WtP : Wt0;
    float bb0 = mat ? pb[colbase + lm] : 0.f;
    float bb1 = mat ? pb[colbase + 16 + lm] : 0.f;
    ushortT* O = mat ? Op : Oh;

    f32x4 acc[4][2];
#pragma unroll
    for (int mt = 0; mt < 4; ++mt)
#pragma unroll
        for (int nt = 0; nt < 2; ++nt) acc[mt][nt] = (f32x4)0.f;

    float4 pf[4];
    g4_loads(X, brow, 0, tid, N, pf);
    g4_write(&S[0], tid, pf);
    __syncthreads();                                   // chunk0 staged
    g4_loads(X, brow, 1, tid, N, pf);                  // chunk1 in flight

#pragma unroll
    for (int kc = 0; kc < 4; ++kc) {
        ushortT* Sc = &S[(kc & 1) * 9216];
        // B for this chunk (16 VGPRs)
        bf16x8 breg[2][2];
#pragma unroll
        for (int nt = 0; nt < 2; ++nt)
#pragma unroll
            for (int ks = 0; ks < 2; ++ks)
                breg[nt][ks] = *(const bf16x8*)&Wt[(size_t)(colbase + nt * 16 + lm) * IN_DIM + kc * 64 + ks * 32 + lk * 8];
#pragma unroll
        for (int ks = 0; ks < 2; ++ks) {
            bf16x8 af[4];
#pragma unroll
            for (int mt = 0; mt < 4; ++mt)
                af[mt] = *(const bf16x8*)&Sc[(rh + mt * 16 + lm) * 72 + ks * 32 + lk * 8];
#pragma unroll
            for (int nt = 0; nt < 2; ++nt)
#pragma unroll
                for (int mt = 0; mt < 4; ++mt)
                    acc[mt][nt] = __builtin_amdgcn_mfma_f32_16x16x32_bf16(af[mt], breg[nt][ks], acc[mt][nt], 0, 0, 0);
        }
        if (kc < 3) {
            g4_write(&S[((kc + 1) & 1) * 9216], tid, pf);   // write staged chunk kc+1
            __syncthreads();                                // ready for next mfma
            if (kc < 2) g4_loads(X, brow, kc + 2, tid, N, pf);  // issue chunk kc+2
        }
    }

    __syncthreads();                               // all A reads done; reuse S as C [128][136]
#pragma unroll
    for (int mt = 0; mt < 4; ++mt)
#pragma unroll
        for (int nt = 0; nt < 2; ++nt) {
            int col = colbase + nt * 16 + lm;
            float bb = nt ? bb1 : bb0;
#pragma unroll
            for (int j = 0; j < 4; ++j) {
                int row = rh + mt * 16 + lk * 4 + j;
                S[row * 136 + col] = f2bf(acc[mt][nt][j] + bb);
            }
        }
    __syncthreads();
    // coalesced stores: 2048 uint4 (128 rows x 16 uint4), 4/thread
#pragma unroll
    for (int i = 0; i < 4; ++i) {
        int idx = i * 512 + tid;
        int row = idx >> 4, colq = idx & 15;
        int gr = brow + row;
        if (gr < N) {
            uint4 v = *(const uint4*)&S[row * 136 + colq * 8];
            *(uint4*)&O[(size_t)gr * 128 + colq * 8] = v;
        }
    }
}

// ---------------- scan hierarchy ----------------

__global__ __launch_bounds__(256) void scan_block_sum(const int* __restrict__ cnt, int* __restrict__ bsum,
                                                      float* __restrict__ dis, int N) {
    __shared__ int s[256];
    int i = blockIdx.x * 256 + threadIdx.x;
    int c = (i < N) ? cnt[i] : -1;
    int v = (i < N) ? c + 1 : 0;
    if (i < N) dis[i] = rsqrtf((float)c + 2.0f);
    s[threadIdx.x] = v;
    __syncthreads();
    for (int o = 128; o > 0; o >>= 1) {
        if (threadIdx.x < o) s[threadIdx.x] += s[threadIdx.x + o];
        __syncthreads();
    }
    if (threadIdx.x == 0) bsum[blockIdx.x] = s[0];
}

__global__ void scan_tops(const int* __restrict__ bsum, int* __restrict__ boff, int* __restrict__ rowptrN, int nb) {
    __shared__ int s[256];
    int t = threadIdx.x;
    int v = (t < nb) ? bsum[t] : 0;
    s[t] = v;
    __syncthreads();
    for (int o = 1; o < 256; o <<= 1) {
        int u = (t >= o) ? s[t - o] : 0;
        __syncthreads();
        s[t] += u;
        __syncthreads();
    }
    if (t < nb) boff[t] = s[t] - v;
    if (t == 255) *rowptrN = s[255];
}

__global__ __launch_bounds__(256) void scan_final(const int* __restrict__ cnt, const int* __restrict__ boff,
                                                  const float* __restrict__ dis,
                                                  int* __restrict__ rowptr, int* __restrict__ cursor,
                                                  int2* __restrict__ recs, int N) {
    __shared__ int s[256];
    int t = threadIdx.x;
    int i = blockIdx.x * 256 + t;
    int v = (i < N) ? cnt[i] + 1 : 0;
    s[t] = v;
    __syncthreads();
    for (int o = 1; o < 256; o <<= 1) {
        int u = (t >= o) ? s[t - o] : 0;
        __syncthreads();
        s[t] += u;
        __syncthreads();
    }
    if (i < N) {
        int e = boff[blockIdx.x] + s[t] - v;
        rowptr[i] = e;
        cursor[i] = e + 1;                    // slot e holds the self record
        float d = dis[i];
        int2 r; r.x = i; r.y = f2i(2.0f * d * d);
        recs[e] = r;
    }
}

// XCD-partitioned fill; writes (src, dis[src]*dis[dst]) records
__global__ __launch_bounds__(256) void fill_xcd(const int* __restrict__ ei, int E, int nper,
                                                const float* __restrict__ dis,
                                                int* __restrict__ cursor, int2* __restrict__ recs) {
    int xcd = blockIdx.x & 7;
    int nchunk = gridDim.x >> 3;
    int chunk = blockIdx.x >> 3;
    int csz = (E + nchunk - 1) / nchunk;
    int beg = chunk * csz;
    int end = min(E, beg + csz);
    for (int e = beg + (int)threadIdx.x; e < end; e += 256) {
        int c = ei[E + e];
        if (c / nper == xcd) {
            int r = ei[e];
            int slot = atomicAdd(&cursor[c], 1);
            int2 rec; rec.x = r; rec.y = f2i(dis[r] * dis[c]);
            recs[slot] = rec;
        }
    }
}

// ---------------- aggregation: wave per node, half-wave split, 4 records in flight per half ----------------

__global__ __launch_bounds__(256) void aggregate_rec(const ushortT* __restrict__ h,
                                                     const int* __restrict__ rowptr,
                                                     const int2* __restrict__ recs,
                                                     ushortT* __restrict__ aggb, int N) {
    int n = blockIdx.x * 4 + (threadIdx.x >> 6);
    if (n >= N) return;
    int lane = threadIdx.x & 63;
    int half = lane >> 5, cl = lane & 31;
    int beg = rowptr[n], end = rowptr[n + 1];
    const uint2* h2 = (const uint2*)h;           // 8B units; row stride 32
    float a0 = 0.f, a1 = 0.f, a2 = 0.f, a3 = 0.f;
    float b0 = 0.f, b1 = 0.f, b2 = 0.f, b3 = 0.f;
    float c0 = 0.f, c1 = 0.f, c2 = 0.f, c3 = 0.f;
    float d0 = 0.f, d1 = 0.f, d2 = 0.f, d3 = 0.f;
    int idx = beg + half;
    // main: 4 records per half per iteration (8 rows in flight per wave)
    for (; idx + 6 < end; idx += 8) {
        int2 r0 = recs[idx];
        int2 r1 = recs[idx + 2];
        int2 r2 = recs[idx + 4];
        int2 r3 = recs[idx + 6];
        uint2 v0 = h2[(size_t)r0.x * 32 + cl];
        uint2 v1 = h2[(size_t)r1.x * 32 + cl];
        uint2 v2 = h2[(size_t)r2.x * 32 + cl];
        uint2 v3 = h2[(size_t)r3.x * 32 + cl];
        float n0 = i2f(r0.y), n1 = i2f(r1.y), n2 = i2f(r2.y), n3 = i2f(r3.y);
        a0 = fmaf(n0, bflo(v0.x), a0); a1 = fmaf(n0, bfhi(v0.x), a1);
        a2 = fmaf(n0, bflo(v0.y), a2); a3 = fmaf(n0, bfhi(v0.y), a3);
        b0 = fmaf(n1, bflo(v1.x), b0); b1 = fmaf(n1, bfhi(v1.x), b1);
        b2 = fmaf(n1, bflo(v1.y), b2); b3 = fmaf(n1, bfhi(v1.y), b3);
        c0 = fmaf(n2, bflo(v2.x), c0); c1 = fmaf(n2, bfhi(v2.x), c1);
        c2 = fmaf(n2, bflo(v2.y), c2); c3 = fmaf(n2, bfhi(v2.y), c3);
        d0 = fmaf(n3, bflo(v3.x), d0); d1 = fmaf(n3, bfhi(v3.x), d1);
        d2 = fmaf(n3, bflo(v3.y), d2); d3 = fmaf(n3, bfhi(v3.y), d3);
    }
    // tail: up to 3 leftover records per half
    for (; idx < end; idx += 2) {
        int2 r0 = recs[idx];
        uint2 v0 = h2[(size_t)r0.x * 32 + cl];
        float n0 = i2f(r0.y);
        a0 = fmaf(n0, bflo(v0.x), a0); a1 = fmaf(n0, bfhi(v0.x), a1);
        a2 = fmaf(n0, bflo(v0.y), a2); a3 = fmaf(n0, bfhi(v0.y), a3);
    }
    a0 = (a0 + b0) + (c0 + d0);
    a1 = (a1 + b1) + (c1 + d1);
    a2 = (a2 + b2) + (c2 + d2);
    a3 = (a3 + b3) + (c3 + d3);
    a0 += __shfl_xor(a0, 32);
    a1 += __shfl_xor(a1, 32);
    a2 += __shfl_xor(a2, 32);
    a3 += __shfl_xor(a3, 32);
    if (half == 0) {
        uint2 o;
        o.x = pk2(a0, a1);
        o.y = pk2(a2, a3);
        ((uint2*)aggb)[(size_t)n * 32 + cl] = o;
    }
}

// ---------------- BN stats from bf16 (raw sums) ----------------

__global__ __launch_bounds__(256) void stats_bf(const unsigned* __restrict__ v, int totalU,
                                                float* __restrict__ sums) {
    int tid = blockIdx.x * 256 + threadIdx.x;
    int stride = gridDim.x * 256;
    float sx = 0.f, sy = 0.f, qx = 0.f, qy = 0.f;
    for (int i = tid; i < totalU; i += stride) {
        unsigned u = v[i];
        float a = bflo(u), b = bfhi(u);
        sx += a; sy += b;
        qx = fmaf(a, a, qx); qy = fmaf(b, b, qy);
    }
    __shared__ float l0[256], l1[256], l2[256], l3[256];
    int t = threadIdx.x;
    l0[t] = sx; l1[t] = sy; l2[t] = qx; l3[t] = qy;
    __syncthreads();
    if (t < 64) {
        sx = (l0[t] + l0[t + 64]) + (l0[t + 128] + l0[t + 192]);
        sy = (l1[t] + l1[t + 64]) + (l1[t + 128] + l1[t + 192]);
        qx = (l2[t] + l2[t + 64]) + (l2[t + 128] + l2[t + 192]);
        qy = (l3[t] + l3[t + 64]) + (l3[t + 128] + l3[t + 192]);
        atomicAdd(&sums[2 * t], sx);
        atomicAdd(&sums[2 * t + 1], sy);
        atomicAdd(&sums[128 + 2 * t], qx);
        atomicAdd(&sums[128 + 2 * t + 1], qy);
    }
}

// ---------------- GEMM1 fused: x1 = relu(bn0(agg)) + proj (written out), h = x1 @ W1, LDS epilogue ----------------

__global__ __launch_bounds__(512) void mgemm1_fused(const uint4* __restrict__ aggb,
                                                    const uint4* __restrict__ projb,
                                                    const float* __restrict__ stats,
                                                    const float* __restrict__ g,
                                                    const float* __restrict__ be,
                                                    const ushortT* __restrict__ Wt1,
                                                    ushortT* __restrict__ O,
                                                    uint4* __restrict__ x1b,
                                                    int N) {
    __shared__ __align__(16) ushortT S[17408];
    __shared__ float sc[128], sh[128];
    int tid = threadIdx.x;
    int brow = blockIdx.x * 128;

    if (tid < 128) {
        float mean = stats[tid] / (float)N;
        float var = stats[128 + tid] / (float)N - mean * mean;
        float inv = rsqrtf(var + EPS);
        float s = g[tid] * inv;
        sc[tid] = s;
        sh[tid] = be[tid] - mean * s;
    }
    __syncthreads();

#pragma unroll
    for (int i = 0; i < 4; ++i) {
        int idx = i * 512 + tid;
        int row = idx >> 4, q = idx & 15;
        int gr = brow + row;
        uint4 a = make_uint4(0u, 0u, 0u, 0u), p = a;
        if (gr < N) {
            size_t gidx = (size_t)gr * 16 + q;
            a = aggb[gidx];
            p = projb[gidx];
        }
        int ch = q * 8;
        float v0 = fmaxf(fmaf(bflo(a.x), sc[ch + 0], sh[ch + 0]), 0.f) + bflo(p.x);
        float v1 = fmaxf(fmaf(bfhi(a.x), sc[ch + 1], sh[ch + 1]), 0.f) + bfhi(p.x);
        float v2 = fmaxf(fmaf(bflo(a.y), sc[ch + 2], sh[ch + 2]), 0.f) + bflo(p.y);
        float v3 = fmaxf(fmaf(bfhi(a.y), sc[ch + 3], sh[ch + 3]), 0.f) + bfhi(p.y);
        float v4 = fmaxf(fmaf(bflo(a.z), sc[ch + 4], sh[ch + 4]), 0.f) + bflo(p.z);
        float v5 = fmaxf(fmaf(bfhi(a.z), sc[ch + 5], sh[ch + 5]), 0.f) + bfhi(p.z);
        float v6 = fmaxf(fmaf(bflo(a.w), sc[ch + 6], sh[ch + 6]), 0.f) + bflo(p.w);
        float v7 = fmaxf(fmaf(bfhi(a.w), sc[ch + 7], sh[ch + 7]), 0.f) + bfhi(p.w);
        uint4 pv;
        pv.x = pk2(v0, v1);
        pv.y = pk2(v2, v3);
        pv.z = pk2(v4, v5);
        pv.w = pk2(v6, v7);
        *(uint4*)&S[row * 136 + q * 8] = pv;
        if (gr < N) x1b[(size_t)gr * 16 + q] = pv;
    }
    __syncthreads();

    int w = tid >> 6, lane = tid & 63;
    int lm = lane & 15, lk = lane >> 4;
    int rh = (w >> 2) * 64;
    int colbase = (w & 3) * 32;

    bf16x8 breg[2][4];
#pragma unroll
    for (int nt = 0; nt < 2; ++nt)
#pragma unroll
        for (int ks = 0; ks < 4; ++ks)
            breg[nt][ks] = *(const bf16x8*)&Wt1[(size_t)(colbase + nt * 16 + lm) * H + ks * 32 + lk * 8];

    f32x4 acc[4][2];
#pragma unroll
    for (int mt = 0; mt < 4; ++mt)
#pragma unroll
        for (int nt = 0; nt < 2; ++nt) acc[mt][nt] = (f32x4)0.f;

#pragma unroll
    for (int ks = 0; ks < 4; ++ks) {
        bf16x8 af[4];
#pragma unroll
        for (int mt = 0; mt < 4; ++mt)
            af[mt] = *(const bf16x8*)&S[(rh + mt * 16 + lm) * 136 + ks * 32 + lk * 8];
#pragma unroll
        for (int nt = 0; nt < 2; ++nt)
#pragma unroll
            for (int mt = 0; mt < 4; ++mt)
                acc[mt][nt] = __builtin_amdgcn_mfma_f32_16x16x32_bf16(af[mt], breg[nt][ks], acc[mt][nt], 0, 0, 0);
    }

    __syncthreads();
#pragma unroll
    for (int mt = 0; mt < 4; ++mt)
#pragma unroll
        for (int nt = 0; nt < 2; ++nt) {
            int col = colbase + nt * 16 + lm;
#pragma unroll
            for (int j = 0; j < 4; ++j) {
                int row = rh + mt * 16 + lk * 4 + j;
                S[row * 136 + col] = f2bf(acc[mt][nt][j]);
            }
        }
    __syncthreads();
#pragma unroll
    for (int i = 0; i < 4; ++i) {
        int idx = i * 512 + tid;
        int row = idx >> 4, colq = idx & 15;
        int gr = brow + row;
        if (gr < N) {
            uint4 v = *(const uint4*)&S[row * 136 + colq * 8];
            *(uint4*)&O[(size_t)gr * 128 + colq * 8] = v;
        }
    }
}

// ---------------- head: out = (relu(bn1(agg)) + x1) @ hW + hb, x2 inline ----------------

__global__ __launch_bounds__(256) void head_fused(const uint4* __restrict__ aggb,
                                                  const uint4* __restrict__ x1b,
                                                  const float* __restrict__ stats,
                                                  const float* __restrict__ g,
                                                  const float* __restrict__ be,
                                                  const ushortT* __restrict__ WtH,
                                                  const float* __restrict__ hb,
                                                  float* __restrict__ out, int N) {
    __shared__ __align__(16) ushortT As[64][136];
    __shared__ __align__(16) ushortT Bs[48][136];
    __shared__ float sc[128], sh[128];

    int tid = threadIdx.x;
    int brow = blockIdx.x * 64;
    int w = tid >> 6, lane = tid & 63;
    int lm = lane & 15, lk = lane >> 4;

    if (tid < 128) {
        float mean = stats[tid] / (float)N;
        float var = stats[128 + tid] / (float)N - mean * mean;
        float inv = rsqrtf(var + EPS);
        float s = g[tid] * inv;
        sc[tid] = s;
        sh[tid] = be[tid] - mean * s;
    }
    if (tid < 192) {
        int row = tid >> 2, q = tid & 3;
        const uint4* src = (const uint4*)&WtH[(size_t)row * H + q * 32];
        uint4 a = src[0], b = src[1], c = src[2], d = src[3];
        uint4* dst = (uint4*)&Bs[row][q * 32];
        dst[0] = a; dst[1] = b; dst[2] = c; dst[3] = d;
    }
    __syncthreads();
#pragma unroll
    for (int k = 0; k < 4; ++k) {
        int idx = k * 256 + tid;
        int row = idx >> 4, colq = idx & 15;
        int gr = brow + row;
        uint4 a = make_uint4(0u, 0u, 0u, 0u), x = a;
        if (gr < N) {
            size_t gidx = (size_t)brow * 16 + idx;
            a = aggb[gidx];
            x = x1b[gidx];
        }
        int ch = colq * 8;
        float v0 = fmaxf(fmaf(bflo(a.x), sc[ch + 0], sh[ch + 0]), 0.f) + bflo(x.x);
        float v1 = fmaxf(fmaf(bfhi(a.x), sc[ch + 1], sh[ch + 1]), 0.f) + bfhi(x.x);
        float v2 = fmaxf(fmaf(bflo(a.y), sc[ch + 2], sh[ch + 2]), 0.f) + bflo(x.y);
        float v3 = fmaxf(fmaf(bfhi(a.y), sc[ch + 3], sh[ch + 3]), 0.f) + bfhi(x.y);
        float v4 = fmaxf(fmaf(bflo(a.z), sc[ch + 4], sh[ch + 4]), 0.f) + bflo(x.z);
        float v5 = fmaxf(fmaf(bfhi(a.z), sc[ch + 5], sh[ch + 5]), 0.f) + bfhi(x.z);
        float v6 = fmaxf(fmaf(bflo(a.w), sc[ch + 6], sh[ch + 6]), 0.f) + bflo(x.w);
        float v7 = fmaxf(fmaf(bfhi(a.w), sc[ch + 7], sh[ch + 7]), 0.f) + bfhi(x.w);
        uint4 pv;
        pv.x = pk2(v0, v1);
        pv.y = pk2(v2, v3);
        pv.z = pk2(v4, v5);
        pv.w = pk2(v6, v7);
        *(uint4*)&As[row][colq * 8] = pv;
    }
    __syncthreads();

    f32x4 acc[3];
#pragma unroll
    for (int nt = 0; nt < 3; ++nt) acc[nt] = (f32x4)0.f;
#pragma unroll
    for (int ks = 0; ks < 4; ++ks) {
        bf16x8 a = *(const bf16x8*)&As[w * 16 + lm][ks * 32 + lk * 8];
#pragma unroll
        for (int nt = 0; nt < 3; ++nt) {
            bf16x8 b = *(const bf16x8*)&Bs[nt * 16 + lm][ks * 32 + lk * 8];
            acc[nt] = __builtin_amdgcn_mfma_f32_16x16x32_bf16(a, b, acc[nt], 0, 0, 0);
        }
    }
#pragma unroll
    for (int nt = 0; nt < 3; ++nt) {
        int col = nt * 16 + lm;
        if (col < OUT_DIM) {
            float bbv = hb[col];
#pragma unroll
            for (int j = 0; j < 4; ++j) {
                int r = brow + w * 16 + lk * 4 + j;
                if (r < N) out[(size_t)r * OUT_DIM + col] = acc[nt][j] + bbv;
            }
        }
    }
}

// ---------------- launch ----------------

extern "C" void kernel_launch(void* const* d_in, const int* in_sizes, int n_in,
                              void* d_out, int out_size, void* d_ws, size_t ws_size,
                              hipStream_t stream) {
    const float* x   = (const float*)d_in[0];
    const int*   ei  = (const int*)d_in[1];
    const float* W0  = (const float*)d_in[2];
    // d_in[3] = b0: cancels in BatchNorm
    const float* g0  = (const float*)d_in[4];
    const float* be0 = (const float*)d_in[5];
    const float* pW  = (const float*)d_in[6];
    const float* pb  = (const float*)d_in[7];
    const float* W1  = (const float*)d_in[8];
    // d_in[9] = b1: cancels in BatchNorm
    const float* g1  = (const float*)d_in[10];
    const float* be1 = (const float*)d_in[11];
    const float* hW  = (const float*)d_in[12];
    const float* hb  = (const float*)d_in[13];
    float* out = (float*)d_out;

    int N = in_sizes[0] / IN_DIM;
    int E = in_sizes[1] / 2;
    size_t NH = (size_t)N * H;

    // workspace layout (all bf16 intermediates)
    ushortT* hb16   = (ushortT*)d_ws;            // [N,128] conv input h
    ushortT* aggb   = hb16 + NH;                 // [N,128] aggregated
    ushortT* projb  = aggb + NH;                 // [N,128] proj (block0)
    ushortT* x1b    = projb + NH;                // [N,128] x1
    float*   dis    = (float*)(x1b + NH);        // [N]
    int*     cnt    = (int*)(dis + N);           // [N]
    int*     rowptr = cnt + N;                   // [N+1]
    int*     cursor = rowptr + (N + 1);          // [N]
    int2*    recs   = (int2*)(cursor + N);       // [E+N] (8B-aligned)
    float*   stats  = (float*)(recs + (E + N));  // [512]: conv0 then conv1
    ushortT* Wt0    = (ushortT*)(stats + 512);   // [128*256]
    ushortT* WtP    = Wt0 + 128 * 256;           // [128*256]
    ushortT* Wt1    = WtP + 128 * 256;           // [128*128]
    ushortT* WtH    = Wt1 + 128 * 128;           // [48*128]
    int*     bsum   = (int*)(WtH + 48 * 128);    // [256]
    int*     boff   = bsum + 256;                // [256]
    float*   stats0 = stats;
    float*   stats1 = stats + 256;

    int nb = (N + 255) / 256;
    int g64 = (N + 63) / 64;
    int g128 = (N + 127) / 128;
    int gAgg = (N + 3) / 4;
    int nper = (N + 7) / 8;
    int gemmBlocks = ((g128 + 7) / 8) * 16;      // XCD-paired: 16 blocks per 8 tiles
    const int CNT_BLOCKS = 1024;                 // count role blocks (disjoint chunks)

    // prep (weights + zero cnt/stats)
    prep_weights<<<196, 256, 0, stream>>>(W0, pW, W1, hW, Wt0, WtP, Wt1, WtH, cnt, stats, N);

    // GEMM0 (BM=128, XCD-paired, 4-deep K pipeline) + degree count in one dispatch
    gemm0_count<<<gemmBlocks + CNT_BLOCKS, 512, 0, stream>>>(x, Wt0, WtP, pb, hb16, projb,
                                                             ei, cnt, N, E,
                                                             gemmBlocks, g128);

    // CSR offsets + records
    scan_block_sum<<<nb, 256, 0, stream>>>(cnt, bsum, dis, N);
    scan_tops<<<1, 256, 0, stream>>>(bsum, boff, &rowptr[N], nb);
    scan_final<<<nb, 256, 0, stream>>>(cnt, boff, dis, rowptr, cursor, recs, N);
    fill_xcd<<<2048, 256, 0, stream>>>(ei, E, nper, dis, cursor, recs);

    // block 0
    aggregate_rec<<<gAgg, 256, 0, stream>>>(hb16, rowptr, recs, aggb, N);
    stats_bf<<<256, 256, 0, stream>>>((const unsigned*)aggb, (int)(NH / 2), stats0);

    // block 1 (x1 = relu(bn0(agg)) + proj fused into GEMM1's staging; x1 also written for head)
    mgemm1_fused<<<g128, 512, 0, stream>>>((const uint4*)aggb, (const uint4*)projb, stats0, g0, be0,
                                           Wt1, hb16, (uint4*)x1b, N);
    aggregate_rec<<<gAgg, 256, 0, stream>>>(hb16, rowptr, recs, aggb, N);
    stats_bf<<<256, 256, 0, stream>>>((const unsigned*)aggb, (int)(NH / 2), stats1);

    // head (x2 computed inline)
    head_fused<<<g64, 256, 0, stream>>>((const uint4*)aggb, (const uint4*)x1b, stats1, g1, be1,
                                        WtH, hb, out, N);
}